// Round 5
// baseline (874.693 us; speedup 1.0000x reference)
//
#include <hip/hip_runtime.h>
#include <hip/hip_bf16.h>
#include <math.h>

#define HID 64
#define SCAN_B 256
#define BSHIFT 7                  // 128 rows per coarse bucket
#define ROWS_PER_B (1 << BSHIFT)

typedef __attribute__((ext_vector_type(4))) float f32x4;
typedef __attribute__((ext_vector_type(4))) short s16x4;

__device__ __forceinline__ ushort f2b(float x) {
    __hip_bfloat16 h = __float2bfloat16(x);
    return *reinterpret_cast<ushort*>(&h);
}
__device__ __forceinline__ float b2f(ushort u) {
    return __uint_as_float(((unsigned)u) << 16);
}

// D = A*B + C, 16x16x16 bf16 MFMA. s_nop covers VALU-write -> MFMA-read hazard.
__device__ __forceinline__ f32x4 mfma16(s16x4 a, s16x4 b, f32x4 c) {
    asm("s_nop 1\n\tv_mfma_f32_16x16x16_bf16 %0, %1, %2, %0"
        : "+v"(c) : "v"(a), "v"(b));
    return c;
}

// ---------------------------------------------------------------------------
// feat (f32) -> bf16 copy, 8 elems/thread
// ---------------------------------------------------------------------------
__global__ __launch_bounds__(256) void cvt_bf16_kernel(const float* __restrict__ x,
                                                       ushort* __restrict__ x16, long n8)
{
    long i = (long)blockIdx.x * 256 + threadIdx.x;
    if (i >= n8) return;
    const float4* s = reinterpret_cast<const float4*>(x) + i * 2;
    float4 a = s[0], b = s[1];
    union { uint4 q; ushort s[8]; } pk;
    pk.s[0] = f2b(a.x); pk.s[1] = f2b(a.y); pk.s[2] = f2b(a.z); pk.s[3] = f2b(a.w);
    pk.s[4] = f2b(b.x); pk.s[5] = f2b(b.y); pk.s[6] = f2b(b.z); pk.s[7] = f2b(b.w);
    reinterpret_cast<uint4*>(x16)[i] = pk.q;
}

// ---------------------------------------------------------------------------
// MFMA node MLP (unchanged from round 3)
// ---------------------------------------------------------------------------
template<bool A_FROM_REGS, bool STORE_GLOBAL>
__device__ __forceinline__ void mfma_stage(
    const s16x4 afr[2][4], const ushort (*Wt)[68], const float* bias,
    ushort (*gld)[68], int w, int l, ushort* dstg, int rbase, int n)
{
    f32x4 acc[2][4];
    #pragma unroll
    for (int ct = 0; ct < 4; ++ct) {
        float bv = bias ? bias[(ct << 4) + (l & 15)] : 0.f;
        acc[0][ct] = (f32x4){bv, bv, bv, bv};
        acc[1][ct] = (f32x4){bv, bv, bv, bv};
    }
    #pragma unroll
    for (int kc = 0; kc < 4; ++kc) {
        s16x4 a0, a1;
        if (A_FROM_REGS) {
            a0 = afr[0][kc]; a1 = afr[1][kc];
        } else {
            a0 = *(const s16x4*)&gld[w*32 +  0 + (l & 15)][((l >> 4) << 2) + (kc << 4)];
            a1 = *(const s16x4*)&gld[w*32 + 16 + (l & 15)][((l >> 4) << 2) + (kc << 4)];
        }
        #pragma unroll
        for (int ct = 0; ct < 4; ++ct) {
            s16x4 b = *(const s16x4*)&Wt[(ct << 4) + (l & 15)][((l >> 4) << 2) + (kc << 4)];
            acc[0][ct] = mfma16(a0, b, acc[0][ct]);
            acc[1][ct] = mfma16(a1, b, acc[1][ct]);
        }
    }
    asm volatile("s_nop 7\n\ts_nop 7");   // MFMA-write -> VALU-read hazard
    #pragma unroll
    for (int rt = 0; rt < 2; ++rt)
    #pragma unroll
    for (int ct = 0; ct < 4; ++ct)
    #pragma unroll
    for (int j = 0; j < 4; ++j) {
        int rloc = w*32 + rt*16 + ((l >> 4) << 2) + j;
        if (STORE_GLOBAL) {
            int rg = rbase + rloc;
            if (rg < n)
                dstg[(size_t)rg * HID + (ct << 4) + (l & 15)] = f2b(acc[rt][ct][j]);
        } else {
            gld[rloc][(ct << 4) + (l & 15)] = f2b(fmaxf(acc[rt][ct][j], 0.f));
        }
    }
}

__global__ __launch_bounds__(256) void node_mlp_mfma(
    const ushort* __restrict__ x16,
    const float* __restrict__ W1, const float* __restrict__ b1,
    const float* __restrict__ W2, const float* __restrict__ b2,
    const float* __restrict__ A12,
    const float* __restrict__ ab,
    ushort* __restrict__ u, ushort* __restrict__ v, int n)
{
    __shared__ ushort Wt[4][64][68];
    __shared__ ushort gld[128][68];
    int tid = threadIdx.x;
    int l = tid & 63, w = tid >> 6;
    int rbase = blockIdx.x * 128;

    const float* Wsrc[4] = { W1, A12, W2, A12 + HID*HID };
    for (int m = 0; m < 4; ++m) {
        const float4* s4 = reinterpret_cast<const float4*>(Wsrc[m]);
        #pragma unroll
        for (int q = 0; q < 4; ++q) {
            float4 t = s4[tid*4 + q];
            int idx = tid*16 + q*4;
            int k = idx >> 6, c = idx & 63;
            Wt[m][c+0][k] = f2b(t.x); Wt[m][c+1][k] = f2b(t.y);
            Wt[m][c+2][k] = f2b(t.z); Wt[m][c+3][k] = f2b(t.w);
        }
    }

    s16x4 afr[2][4];
    #pragma unroll
    for (int rt = 0; rt < 2; ++rt) {
        int r = rbase + w*32 + rt*16 + (l & 15);
        int rc = min(r, n - 1);
        const ushort* xr = x16 + (size_t)rc * HID + ((l >> 4) << 2);
        #pragma unroll
        for (int kc = 0; kc < 4; ++kc)
            afr[rt][kc] = *(const s16x4*)(xr + (kc << 4));
    }
    __syncthreads();

    mfma_stage<true,  false>(afr, Wt[0], b1,      gld, w, l, nullptr, rbase, n);
    mfma_stage<false, true >(afr, Wt[1], ab,      gld, w, l, u,       rbase, n);
    mfma_stage<true,  false>(afr, Wt[2], b2,      gld, w, l, nullptr, rbase, n);
    mfma_stage<false, true >(afr, Wt[3], nullptr, gld, w, l, v,       rbase, n);
}

// ---------------------------------------------------------------------------
// CSR build: hist -> scan -> coarse bucket scatter -> fine in-bucket scatter
// ---------------------------------------------------------------------------
__global__ __launch_bounds__(256) void hist_kernel(const int* __restrict__ row,
                                                   int* __restrict__ cnt, int E)
{
    int e = blockIdx.x * 256 + threadIdx.x;
    if (e < E) atomicAdd(&cnt[row[e]], 1);
}

__global__ __launch_bounds__(SCAN_B) void scan1_kernel(const int* __restrict__ cnt,
                                                       int* __restrict__ ptr,
                                                       int* __restrict__ bsum, int n)
{
    __shared__ int lds[SCAN_B];
    int i = blockIdx.x * SCAN_B + threadIdx.x;
    int vin = (i < n) ? cnt[i] : 0;
    int val = vin;
    lds[threadIdx.x] = val;
    __syncthreads();
    for (int off = 1; off < SCAN_B; off <<= 1) {
        int t = (threadIdx.x >= off) ? lds[threadIdx.x - off] : 0;
        __syncthreads();
        val += t;
        lds[threadIdx.x] = val;
        __syncthreads();
    }
    if (i < n) ptr[i] = val - vin;
    if (threadIdx.x == SCAN_B - 1) bsum[blockIdx.x] = val;
}

__global__ __launch_bounds__(1024) void scan2_kernel(const int* __restrict__ bsum,
                                                     int* __restrict__ boffs, int nb)
{
    __shared__ int lds[1024];
    int i = threadIdx.x;
    int vin = (i < nb) ? bsum[i] : 0;
    int val = vin;
    lds[i] = val;
    __syncthreads();
    for (int off = 1; off < 1024; off <<= 1) {
        int t = (i >= off) ? lds[i - off] : 0;
        __syncthreads();
        val += t;
        lds[i] = val;
        __syncthreads();
    }
    if (i < nb) boffs[i] = val - vin;
}

__global__ __launch_bounds__(SCAN_B) void scan3_kernel(int* __restrict__ ptr,
                                                       const int* __restrict__ boffs,
                                                       int n, int E)
{
    int i = blockIdx.x * SCAN_B + threadIdx.x;
    if (i < n) ptr[i] += boffs[blockIdx.x];
    if (i == 0) ptr[n] = E;
}

// coarse: edges -> bucket-grouped tmp array (writes advance sequentially per bucket)
__global__ __launch_bounds__(256) void coarse_scatter(const int* __restrict__ row,
                                                      const int* __restrict__ col,
                                                      const int* __restrict__ ptr,
                                                      int* __restrict__ bcnt,
                                                      int2* __restrict__ tmp,
                                                      int n, int E)
{
    int e = blockIdx.x * 256 + threadIdx.x;
    if (e >= E) return;
    int r = row[e], c = col[e];
    int b = r >> BSHIFT;
    int base = ptr[b << BSHIFT];          // bucket region start (exact)
    int pos = base + atomicAdd(&bcnt[b], 1);
    tmp[pos] = make_int2(r, c);
}

// fine: one workgroup per bucket; per-row cursors in LDS; writes stay in-region
__global__ __launch_bounds__(256) void fine_scatter(const int2* __restrict__ tmp,
                                                    const int* __restrict__ ptr,
                                                    int2* __restrict__ rc_sorted,
                                                    int n, int E)
{
    __shared__ int cur[ROWS_PER_B];
    int b = blockIdx.x;
    int row0 = b << BSHIFT;
    if (threadIdx.x < ROWS_PER_B) {
        int r = row0 + threadIdx.x;
        cur[threadIdx.x] = (r < n) ? ptr[r] : E;
    }
    __syncthreads();
    int start = ptr[min(row0, n)];
    int end   = ptr[min(row0 + ROWS_PER_B, n)];
    for (int e = start + threadIdx.x; e < end; e += 256) {
        int2 rc = tmp[e];
        int pos = atomicAdd(&cur[rc.x & (ROWS_PER_B - 1)], 1);
        rc_sorted[pos] = rc;
    }
}

// ---------------------------------------------------------------------------
// Edge mask: 16 lanes per edge, packed (row,col) read
// ---------------------------------------------------------------------------
__global__ __launch_bounds__(256) void edge_mask16(
    const ushort* __restrict__ u, const ushort* __restrict__ v,
    const float* __restrict__ w2, const float* __restrict__ b2p,
    const int2* __restrict__ rc_sorted,
    float* __restrict__ mask_sorted, int E)
{
    int g = (blockIdx.x * 256 + threadIdx.x) >> 4;
    if (g >= E) return;
    int sub = threadIdx.x & 15;
    int2 rc = rc_sorted[g];
    ushort4 uu = *reinterpret_cast<const ushort4*>(u + (size_t)rc.x * HID + sub * 4);
    ushort4 vv = *reinterpret_cast<const ushort4*>(v + (size_t)rc.y * HID + sub * 4);
    float4 ww = *reinterpret_cast<const float4*>(w2 + sub * 4);
    float p = fmaxf(b2f(uu.x) + b2f(vv.x), 0.f) * ww.x;
    p = fmaf(fmaxf(b2f(uu.y) + b2f(vv.y), 0.f), ww.y, p);
    p = fmaf(fmaxf(b2f(uu.z) + b2f(vv.z), 0.f), ww.z, p);
    p = fmaf(fmaxf(b2f(uu.w) + b2f(vv.w), 0.f), ww.w, p);
    p += __shfl_xor(p, 1, 64);
    p += __shfl_xor(p, 2, 64);
    p += __shfl_xor(p, 4, 64);
    p += __shfl_xor(p, 8, 64);
    if (sub == 0) {
        float la = p + b2p[0];
        float s = 1.f / (1.f + __expf(-la));
        mask_sorted[g] = fminf(fmaxf(fmaf(s, 1.5f, -0.45f), 0.f), 1.f);
    }
}

__global__ __launch_bounds__(256) void rowsum_dinv(
    const float* __restrict__ mask_sorted, const int* __restrict__ ptr,
    float* __restrict__ dinv, int n)
{
    int i = blockIdx.x * 256 + threadIdx.x;
    if (i >= n) return;
    int s0 = ptr[i], s1 = ptr[i + 1];
    float s = 1e-6f;
    for (int e = s0; e < s1; ++e) s += mask_sorted[e];
    float d = 1.f / sqrtf(s);
    dinv[i] = fminf(d, 10.f);
}

// ---------------------------------------------------------------------------
// Aggregation: wave-per-node, bf16 x gather, f32 accumulate.
// ---------------------------------------------------------------------------
__global__ __launch_bounds__(256) void agg_csr(
    const ushort* __restrict__ x16,
    const float* __restrict__ mask_sorted, const float* __restrict__ dinv,
    const int* __restrict__ ptr, const int2* __restrict__ rc_sorted,
    const float* __restrict__ base_in, float* __restrict__ out,
    ushort* __restrict__ x16_out, int n)
{
    int wid = (blockIdx.x * 256 + threadIdx.x) >> 6;
    if (wid >= n) return;
    int lane = threadIdx.x & 63;
    int start = ptr[wid], end = ptr[wid + 1];
    int deg = end - start;
    float acc = 0.f;
    for (int base = 0; base < deg; base += 64) {
        int mcnt = min(64, deg - base);
        int cc = 0; float wv = 0.f;
        if (lane < mcnt) {
            cc = rc_sorted[start + base + lane].y;
            wv = mask_sorted[start + base + lane] * dinv[cc];
        }
        for (int j = 0; j < mcnt; ++j) {
            int c = __shfl(cc, j, 64);
            float wj = __shfl(wv, j, 64);
            float xv = b2f(x16[(size_t)c * HID + lane]);
            acc = fmaf(wj, xv, acc);
        }
    }
    float res = acc * dinv[wid];
    size_t o = (size_t)wid * HID + lane;
    out[o] = base_in[o] + res;
    x16_out[o] = f2b(res);
}

// ---------------------------------------------------------------------------

extern "C" void kernel_launch(void* const* d_in, const int* in_sizes, int n_in,
                              void* d_out, int out_size, void* d_ws, size_t ws_size,
                              hipStream_t stream)
{
    const float* feat  = (const float*)d_in[0];
    const float* nbW   = (const float*)d_in[1];
    const float* nbb   = (const float*)d_in[2];
    const float* selfW = (const float*)d_in[3];
    const float* selfb = (const float*)d_in[4];
    const float* a1W   = (const float*)d_in[5];
    const float* a1b   = (const float*)d_in[6];
    const float* a2W   = (const float*)d_in[7];
    const float* a2b   = (const float*)d_in[8];
    const int*   row   = (const int*)d_in[9];
    const int*   col   = (const int*)d_in[10];
    float* out = (float*)d_out;

    const int n = in_sizes[0] / HID;
    const int E = in_sizes[9];
    const int L = in_sizes[1] / (HID * HID);
    const size_t NH = (size_t)n * HID;
    const int NB = (n + ROWS_PER_B - 1) >> BSHIFT;

    char* p = (char*)d_ws;
    ushort* u          = (ushort*)p; p += NH * 2;
    ushort* v          = (ushort*)p; p += NH * 2;
    ushort* x16a       = (ushort*)p; p += NH * 2;
    ushort* x16b       = (ushort*)p; p += NH * 2;
    float* dinv        = (float*)p;  p += (size_t)n * 4;
    float* mask_sorted = (float*)p;  p += (size_t)E * 4;
    int2*  rc_sorted   = (int2*)p;   p += (size_t)E * 8;
    int2*  tmp_rc      = (int2*)p;   p += (size_t)E * 8;
    int*   ptr         = (int*)p;    p += (size_t)(n + 1) * 4;
    int*   cnt         = (int*)p;    p += (size_t)n * 4;
    int*   bsum        = (int*)p;    p += 1024 * 4;
    int*   boffs       = (int*)p;    p += 1024 * 4;
    int*   bcnt        = (int*)p;    p += (size_t)NB * 4;

    const int eBlocks = (E + 255) / 256;
    const int sBlocks = (n + SCAN_B - 1) / SCAN_B;
    const int wBlocks = (int)(((size_t)n * 64 + 255) / 256);
    const int mBlocks = (E + 15) / 16;
    const int nodeBlocks = (n + 127) / 128;

    // CSR build (once)
    hipMemsetAsync(cnt, 0, (size_t)n * sizeof(int), stream);
    hipMemsetAsync(bcnt, 0, (size_t)NB * sizeof(int), stream);
    hist_kernel<<<eBlocks, 256, 0, stream>>>(row, cnt, E);
    scan1_kernel<<<sBlocks, SCAN_B, 0, stream>>>(cnt, ptr, bsum, n);
    scan2_kernel<<<1, 1024, 0, stream>>>(bsum, boffs, sBlocks);
    scan3_kernel<<<sBlocks, SCAN_B, 0, stream>>>(ptr, boffs, n, E);
    coarse_scatter<<<eBlocks, 256, 0, stream>>>(row, col, ptr, bcnt, tmp_rc, n, E);
    fine_scatter<<<NB, 256, 0, stream>>>(tmp_rc, ptr, rc_sorted, n, E);

    // feat -> bf16 (layer-0 x)
    cvt_bf16_kernel<<<(int)((NH / 8 + 255) / 256), 256, 0, stream>>>(feat, x16a, (long)(NH / 8));

    const ushort* x_in = x16a;
    ushort* x_out = x16b;
    for (int l = 0; l < L; ++l) {
        node_mlp_mfma<<<nodeBlocks, 256, 0, stream>>>(
            x_in,
            nbW + (size_t)l * HID * HID,   nbb + (size_t)l * HID,
            selfW + (size_t)l * HID * HID, selfb + (size_t)l * HID,
            a1W + (size_t)l * 2 * HID * HID,
            a1b + (size_t)l * HID,
            u, v, n);

        edge_mask16<<<mBlocks, 256, 0, stream>>>(
            u, v, a2W + (size_t)l * HID, a2b + l,
            rc_sorted, mask_sorted, E);

        rowsum_dinv<<<(n + 255) / 256, 256, 0, stream>>>(mask_sorted, ptr, dinv, n);

        agg_csr<<<wBlocks, 256, 0, stream>>>(
            x_in, mask_sorted, dinv, ptr, rc_sorted,
            (l == 0) ? feat : out, out, x_out, n);

        ushort* t = (ushort*)x_in;
        x_in = x_out;
        x_out = (l == 0) ? x16a : t;
    }
}

// Round 6
// 671.643 us; speedup vs baseline: 1.3023x; 1.3023x over previous
//
#include <hip/hip_runtime.h>
#include <hip/hip_bf16.h>
#include <math.h>

#define HID 64
#define SCAN_B 256

typedef __attribute__((ext_vector_type(4))) float f32x4;
typedef __attribute__((ext_vector_type(4))) short s16x4;

__device__ __forceinline__ ushort f2b(float x) {
    __hip_bfloat16 h = __float2bfloat16(x);
    return *reinterpret_cast<ushort*>(&h);
}
__device__ __forceinline__ float b2f(ushort u) {
    return __uint_as_float(((unsigned)u) << 16);
}

// D = A*B + C, 16x16x16 bf16 MFMA. s_nop covers VALU-write -> MFMA-read hazard.
__device__ __forceinline__ f32x4 mfma16(s16x4 a, s16x4 b, f32x4 c) {
    asm("s_nop 1\n\tv_mfma_f32_16x16x16_bf16 %0, %1, %2, %0"
        : "+v"(c) : "v"(a), "v"(b));
    return c;
}

// ---------------------------------------------------------------------------
// feat (f32) -> bf16 copy, 8 elems/thread
// ---------------------------------------------------------------------------
__global__ __launch_bounds__(256) void cvt_bf16_kernel(const float* __restrict__ x,
                                                       ushort* __restrict__ x16, long n8)
{
    long i = (long)blockIdx.x * 256 + threadIdx.x;
    if (i >= n8) return;
    const float4* s = reinterpret_cast<const float4*>(x) + i * 2;
    float4 a = s[0], b = s[1];
    union { uint4 q; ushort s[8]; } pk;
    pk.s[0] = f2b(a.x); pk.s[1] = f2b(a.y); pk.s[2] = f2b(a.z); pk.s[3] = f2b(a.w);
    pk.s[4] = f2b(b.x); pk.s[5] = f2b(b.y); pk.s[6] = f2b(b.z); pk.s[7] = f2b(b.w);
    reinterpret_cast<uint4*>(x16)[i] = pk.q;
}

// ---------------------------------------------------------------------------
// MFMA node MLP. Block = 256 thr (4 waves), M-tile = 128 nodes.
// ---------------------------------------------------------------------------
template<bool A_FROM_REGS, bool STORE_GLOBAL>
__device__ __forceinline__ void mfma_stage(
    const s16x4 afr[2][4], const ushort (*Wt)[68], const float* bias,
    ushort (*gld)[68], int w, int l, ushort* dstg, int rbase, int n)
{
    f32x4 acc[2][4];
    #pragma unroll
    for (int ct = 0; ct < 4; ++ct) {
        float bv = bias ? bias[(ct << 4) + (l & 15)] : 0.f;
        acc[0][ct] = (f32x4){bv, bv, bv, bv};
        acc[1][ct] = (f32x4){bv, bv, bv, bv};
    }
    #pragma unroll
    for (int kc = 0; kc < 4; ++kc) {
        s16x4 a0, a1;
        if (A_FROM_REGS) {
            a0 = afr[0][kc]; a1 = afr[1][kc];
        } else {
            a0 = *(const s16x4*)&gld[w*32 +  0 + (l & 15)][((l >> 4) << 2) + (kc << 4)];
            a1 = *(const s16x4*)&gld[w*32 + 16 + (l & 15)][((l >> 4) << 2) + (kc << 4)];
        }
        #pragma unroll
        for (int ct = 0; ct < 4; ++ct) {
            s16x4 b = *(const s16x4*)&Wt[(ct << 4) + (l & 15)][((l >> 4) << 2) + (kc << 4)];
            acc[0][ct] = mfma16(a0, b, acc[0][ct]);
            acc[1][ct] = mfma16(a1, b, acc[1][ct]);
        }
    }
    asm volatile("s_nop 7\n\ts_nop 7");   // MFMA-write -> VALU-read hazard
    #pragma unroll
    for (int rt = 0; rt < 2; ++rt)
    #pragma unroll
    for (int ct = 0; ct < 4; ++ct)
    #pragma unroll
    for (int j = 0; j < 4; ++j) {
        int rloc = w*32 + rt*16 + ((l >> 4) << 2) + j;
        if (STORE_GLOBAL) {
            int rg = rbase + rloc;
            if (rg < n)
                dstg[(size_t)rg * HID + (ct << 4) + (l & 15)] = f2b(acc[rt][ct][j]);
        } else {
            gld[rloc][(ct << 4) + (l & 15)] = f2b(fmaxf(acc[rt][ct][j], 0.f));
        }
    }
}

__global__ __launch_bounds__(256) void node_mlp_mfma(
    const ushort* __restrict__ x16,
    const float* __restrict__ W1, const float* __restrict__ b1,
    const float* __restrict__ W2, const float* __restrict__ b2,
    const float* __restrict__ A12,
    const float* __restrict__ ab,
    ushort* __restrict__ u, ushort* __restrict__ v, int n)
{
    __shared__ ushort Wt[4][64][68];
    __shared__ ushort gld[128][68];
    int tid = threadIdx.x;
    int l = tid & 63, w = tid >> 6;
    int rbase = blockIdx.x * 128;

    const float* Wsrc[4] = { W1, A12, W2, A12 + HID*HID };
    for (int m = 0; m < 4; ++m) {
        const float4* s4 = reinterpret_cast<const float4*>(Wsrc[m]);
        #pragma unroll
        for (int q = 0; q < 4; ++q) {
            float4 t = s4[tid*4 + q];
            int idx = tid*16 + q*4;
            int k = idx >> 6, c = idx & 63;
            Wt[m][c+0][k] = f2b(t.x); Wt[m][c+1][k] = f2b(t.y);
            Wt[m][c+2][k] = f2b(t.z); Wt[m][c+3][k] = f2b(t.w);
        }
    }

    s16x4 afr[2][4];
    #pragma unroll
    for (int rt = 0; rt < 2; ++rt) {
        int r = rbase + w*32 + rt*16 + (l & 15);
        int rc = min(r, n - 1);
        const ushort* xr = x16 + (size_t)rc * HID + ((l >> 4) << 2);
        #pragma unroll
        for (int kc = 0; kc < 4; ++kc)
            afr[rt][kc] = *(const s16x4*)(xr + (kc << 4));
    }
    __syncthreads();

    mfma_stage<true,  false>(afr, Wt[0], b1,      gld, w, l, nullptr, rbase, n);
    mfma_stage<false, true >(afr, Wt[1], ab,      gld, w, l, u,       rbase, n);
    mfma_stage<true,  false>(afr, Wt[2], b2,      gld, w, l, nullptr, rbase, n);
    mfma_stage<false, true >(afr, Wt[3], nullptr, gld, w, l, v,       rbase, n);
}

// ---------------------------------------------------------------------------
// CSR build: hist -> 2-level scan -> single-pass packed scatter
// ---------------------------------------------------------------------------
__global__ __launch_bounds__(256) void hist_kernel(const int* __restrict__ row,
                                                   int* __restrict__ cnt, int E)
{
    int e = blockIdx.x * 256 + threadIdx.x;
    if (e < E) atomicAdd(&cnt[row[e]], 1);
}

__global__ __launch_bounds__(SCAN_B) void scan1_kernel(const int* __restrict__ cnt,
                                                       int* __restrict__ ptr,
                                                       int* __restrict__ bsum, int n)
{
    __shared__ int lds[SCAN_B];
    int i = blockIdx.x * SCAN_B + threadIdx.x;
    int vin = (i < n) ? cnt[i] : 0;
    int val = vin;
    lds[threadIdx.x] = val;
    __syncthreads();
    for (int off = 1; off < SCAN_B; off <<= 1) {
        int t = (threadIdx.x >= off) ? lds[threadIdx.x - off] : 0;
        __syncthreads();
        val += t;
        lds[threadIdx.x] = val;
        __syncthreads();
    }
    if (i < n) ptr[i] = val - vin;
    if (threadIdx.x == SCAN_B - 1) bsum[blockIdx.x] = val;
}

__global__ __launch_bounds__(1024) void scan2_kernel(const int* __restrict__ bsum,
                                                     int* __restrict__ boffs, int nb)
{
    __shared__ int lds[1024];
    int i = threadIdx.x;
    int vin = (i < nb) ? bsum[i] : 0;
    int val = vin;
    lds[i] = val;
    __syncthreads();
    for (int off = 1; off < 1024; off <<= 1) {
        int t = (i >= off) ? lds[i - off] : 0;
        __syncthreads();
        val += t;
        lds[i] = val;
        __syncthreads();
    }
    if (i < nb) boffs[i] = val - vin;
}

__global__ __launch_bounds__(SCAN_B) void scan3_kernel(int* __restrict__ ptr,
                                                       const int* __restrict__ boffs,
                                                       int n, int E)
{
    int i = blockIdx.x * SCAN_B + threadIdx.x;
    if (i < n) ptr[i] += boffs[blockIdx.x];
    if (i == 0) ptr[n] = E;
}

// single-pass: per-row cursors (low contention, ~12 edges/row), packed int2 store
__global__ __launch_bounds__(256) void scatter_kernel(const int* __restrict__ row,
                                                      const int* __restrict__ col,
                                                      int* __restrict__ wpos,
                                                      int2* __restrict__ rc_sorted, int E)
{
    int e = blockIdx.x * 256 + threadIdx.x;
    if (e >= E) return;
    int r = row[e], c = col[e];
    int pos = atomicAdd(&wpos[r], 1);
    rc_sorted[pos] = make_int2(r, c);
}

// ---------------------------------------------------------------------------
// Edge mask: 16 lanes per edge, packed (row,col) read
// ---------------------------------------------------------------------------
__global__ __launch_bounds__(256) void edge_mask16(
    const ushort* __restrict__ u, const ushort* __restrict__ v,
    const float* __restrict__ w2, const float* __restrict__ b2p,
    const int2* __restrict__ rc_sorted,
    float* __restrict__ mask_sorted, int E)
{
    int g = (blockIdx.x * 256 + threadIdx.x) >> 4;
    if (g >= E) return;
    int sub = threadIdx.x & 15;
    int2 rc = rc_sorted[g];
    ushort4 uu = *reinterpret_cast<const ushort4*>(u + (size_t)rc.x * HID + sub * 4);
    ushort4 vv = *reinterpret_cast<const ushort4*>(v + (size_t)rc.y * HID + sub * 4);
    float4 ww = *reinterpret_cast<const float4*>(w2 + sub * 4);
    float p = fmaxf(b2f(uu.x) + b2f(vv.x), 0.f) * ww.x;
    p = fmaf(fmaxf(b2f(uu.y) + b2f(vv.y), 0.f), ww.y, p);
    p = fmaf(fmaxf(b2f(uu.z) + b2f(vv.z), 0.f), ww.z, p);
    p = fmaf(fmaxf(b2f(uu.w) + b2f(vv.w), 0.f), ww.w, p);
    p += __shfl_xor(p, 1, 64);
    p += __shfl_xor(p, 2, 64);
    p += __shfl_xor(p, 4, 64);
    p += __shfl_xor(p, 8, 64);
    if (sub == 0) {
        float la = p + b2p[0];
        float s = 1.f / (1.f + __expf(-la));
        mask_sorted[g] = fminf(fmaxf(fmaf(s, 1.5f, -0.45f), 0.f), 1.f);
    }
}

__global__ __launch_bounds__(256) void rowsum_dinv(
    const float* __restrict__ mask_sorted, const int* __restrict__ ptr,
    float* __restrict__ dinv, int n)
{
    int i = blockIdx.x * 256 + threadIdx.x;
    if (i >= n) return;
    int s0 = ptr[i], s1 = ptr[i + 1];
    float s = 1e-6f;
    for (int e = s0; e < s1; ++e) s += mask_sorted[e];
    float d = 1.f / sqrtf(s);
    dinv[i] = fminf(d, 10.f);
}

// ---------------------------------------------------------------------------
// Aggregation: wave-per-node, bf16 x gather, f32 accumulate.
// ---------------------------------------------------------------------------
__global__ __launch_bounds__(256) void agg_csr(
    const ushort* __restrict__ x16,
    const float* __restrict__ mask_sorted, const float* __restrict__ dinv,
    const int* __restrict__ ptr, const int2* __restrict__ rc_sorted,
    const float* __restrict__ base_in, float* __restrict__ out,
    ushort* __restrict__ x16_out, int n)
{
    int wid = (blockIdx.x * 256 + threadIdx.x) >> 6;
    if (wid >= n) return;
    int lane = threadIdx.x & 63;
    int start = ptr[wid], end = ptr[wid + 1];
    int deg = end - start;
    float acc = 0.f;
    for (int base = 0; base < deg; base += 64) {
        int mcnt = min(64, deg - base);
        int cc = 0; float wv = 0.f;
        if (lane < mcnt) {
            cc = rc_sorted[start + base + lane].y;
            wv = mask_sorted[start + base + lane] * dinv[cc];
        }
        for (int j = 0; j < mcnt; ++j) {
            int c = __shfl(cc, j, 64);
            float wj = __shfl(wv, j, 64);
            float xv = b2f(x16[(size_t)c * HID + lane]);
            acc = fmaf(wj, xv, acc);
        }
    }
    float res = acc * dinv[wid];
    size_t o = (size_t)wid * HID + lane;
    out[o] = base_in[o] + res;
    x16_out[o] = f2b(res);
}

// ---------------------------------------------------------------------------

extern "C" void kernel_launch(void* const* d_in, const int* in_sizes, int n_in,
                              void* d_out, int out_size, void* d_ws, size_t ws_size,
                              hipStream_t stream)
{
    const float* feat  = (const float*)d_in[0];
    const float* nbW   = (const float*)d_in[1];
    const float* nbb   = (const float*)d_in[2];
    const float* selfW = (const float*)d_in[3];
    const float* selfb = (const float*)d_in[4];
    const float* a1W   = (const float*)d_in[5];
    const float* a1b   = (const float*)d_in[6];
    const float* a2W   = (const float*)d_in[7];
    const float* a2b   = (const float*)d_in[8];
    const int*   row   = (const int*)d_in[9];
    const int*   col   = (const int*)d_in[10];
    float* out = (float*)d_out;

    const int n = in_sizes[0] / HID;
    const int E = in_sizes[9];
    const int L = in_sizes[1] / (HID * HID);
    const size_t NH = (size_t)n * HID;

    char* p = (char*)d_ws;
    ushort* u          = (ushort*)p; p += NH * 2;
    ushort* v          = (ushort*)p; p += NH * 2;
    ushort* x16a       = (ushort*)p; p += NH * 2;
    ushort* x16b       = (ushort*)p; p += NH * 2;
    float* dinv        = (float*)p;  p += (size_t)n * 4;
    float* mask_sorted = (float*)p;  p += (size_t)E * 4;
    int2*  rc_sorted   = (int2*)p;   p += (size_t)E * 8;
    int*   ptr         = (int*)p;    p += (size_t)(n + 1) * 4;
    int*   cnt         = (int*)p;    p += (size_t)n * 4;
    int*   bsum        = (int*)p;    p += 1024 * 4;
    int*   boffs       = (int*)p;    p += 1024 * 4;

    const int eBlocks = (E + 255) / 256;
    const int sBlocks = (n + SCAN_B - 1) / SCAN_B;
    const int wBlocks = (int)(((size_t)n * 64 + 255) / 256);
    const int mBlocks = (E + 15) / 16;
    const int nodeBlocks = (n + 127) / 128;

    // CSR build (once per call)
    hipMemsetAsync(cnt, 0, (size_t)n * sizeof(int), stream);
    hist_kernel<<<eBlocks, 256, 0, stream>>>(row, cnt, E);
    scan1_kernel<<<sBlocks, SCAN_B, 0, stream>>>(cnt, ptr, bsum, n);
    scan2_kernel<<<1, 1024, 0, stream>>>(bsum, boffs, sBlocks);
    scan3_kernel<<<sBlocks, SCAN_B, 0, stream>>>(ptr, boffs, n, E);
    hipMemcpyAsync(cnt, ptr, (size_t)n * sizeof(int), hipMemcpyDeviceToDevice, stream);
    scatter_kernel<<<eBlocks, 256, 0, stream>>>(row, col, cnt, rc_sorted, E);

    // feat -> bf16 (layer-0 x)
    cvt_bf16_kernel<<<(int)((NH / 8 + 255) / 256), 256, 0, stream>>>(feat, x16a, (long)(NH / 8));

    const ushort* x_in = x16a;
    ushort* x_out = x16b;
    for (int l = 0; l < L; ++l) {
        node_mlp_mfma<<<nodeBlocks, 256, 0, stream>>>(
            x_in,
            nbW + (size_t)l * HID * HID,   nbb + (size_t)l * HID,
            selfW + (size_t)l * HID * HID, selfb + (size_t)l * HID,
            a1W + (size_t)l * 2 * HID * HID,
            a1b + (size_t)l * HID,
            u, v, n);

        edge_mask16<<<mBlocks, 256, 0, stream>>>(
            u, v, a2W + (size_t)l * HID, a2b + l,
            rc_sorted, mask_sorted, E);

        rowsum_dinv<<<(n + 255) / 256, 256, 0, stream>>>(mask_sorted, ptr, dinv, n);

        agg_csr<<<wBlocks, 256, 0, stream>>>(
            x_in, mask_sorted, dinv, ptr, rc_sorted,
            (l == 0) ? feat : out, out, x_out, n);

        ushort* t = (ushort*)x_in;
        x_in = x_out;
        x_out = (l == 0) ? x16a : t;
    }
}

// Round 7
// 563.518 us; speedup vs baseline: 1.5522x; 1.1919x over previous
//
#include <hip/hip_runtime.h>
#include <hip/hip_bf16.h>
#include <math.h>

#define HID 64
#define SCAN_B 256

typedef __attribute__((ext_vector_type(4))) float f32x4;
typedef __attribute__((ext_vector_type(4))) short s16x4;

__device__ __forceinline__ ushort f2b(float x) {
    __hip_bfloat16 h = __float2bfloat16(x);
    return *reinterpret_cast<ushort*>(&h);
}
__device__ __forceinline__ float b2f(ushort u) {
    return __uint_as_float(((unsigned)u) << 16);
}

// D = A*B + C, 16x16x16 bf16 MFMA. s_nop covers VALU-write -> MFMA-read hazard.
__device__ __forceinline__ f32x4 mfma16(s16x4 a, s16x4 b, f32x4 c) {
    asm("s_nop 1\n\tv_mfma_f32_16x16x16_bf16 %0, %1, %2, %0"
        : "+v"(c) : "v"(a), "v"(b));
    return c;
}

// ---------------------------------------------------------------------------
// feat (f32) -> bf16 copy, 8 elems/thread
// ---------------------------------------------------------------------------
__global__ __launch_bounds__(256) void cvt_bf16_kernel(const float* __restrict__ x,
                                                       ushort* __restrict__ x16, long n8)
{
    long i = (long)blockIdx.x * 256 + threadIdx.x;
    if (i >= n8) return;
    const float4* s = reinterpret_cast<const float4*>(x) + i * 2;
    float4 a = s[0], b = s[1];
    union { uint4 q; ushort s[8]; } pk;
    pk.s[0] = f2b(a.x); pk.s[1] = f2b(a.y); pk.s[2] = f2b(a.z); pk.s[3] = f2b(a.w);
    pk.s[4] = f2b(b.x); pk.s[5] = f2b(b.y); pk.s[6] = f2b(b.z); pk.s[7] = f2b(b.w);
    reinterpret_cast<uint4*>(x16)[i] = pk.q;
}

// ---------------------------------------------------------------------------
// MFMA node MLP. Block = 256 thr (4 waves), M-tile = 128 nodes.
// ---------------------------------------------------------------------------
template<bool A_FROM_REGS, bool STORE_GLOBAL>
__device__ __forceinline__ void mfma_stage(
    const s16x4 afr[2][4], const ushort (*Wt)[68], const float* bias,
    ushort (*gld)[68], int w, int l, ushort* dstg, int rbase, int n)
{
    f32x4 acc[2][4];
    #pragma unroll
    for (int ct = 0; ct < 4; ++ct) {
        float bv = bias ? bias[(ct << 4) + (l & 15)] : 0.f;
        acc[0][ct] = (f32x4){bv, bv, bv, bv};
        acc[1][ct] = (f32x4){bv, bv, bv, bv};
    }
    #pragma unroll
    for (int kc = 0; kc < 4; ++kc) {
        s16x4 a0, a1;
        if (A_FROM_REGS) {
            a0 = afr[0][kc]; a1 = afr[1][kc];
        } else {
            a0 = *(const s16x4*)&gld[w*32 +  0 + (l & 15)][((l >> 4) << 2) + (kc << 4)];
            a1 = *(const s16x4*)&gld[w*32 + 16 + (l & 15)][((l >> 4) << 2) + (kc << 4)];
        }
        #pragma unroll
        for (int ct = 0; ct < 4; ++ct) {
            s16x4 b = *(const s16x4*)&Wt[(ct << 4) + (l & 15)][((l >> 4) << 2) + (kc << 4)];
            acc[0][ct] = mfma16(a0, b, acc[0][ct]);
            acc[1][ct] = mfma16(a1, b, acc[1][ct]);
        }
    }
    asm volatile("s_nop 7\n\ts_nop 7");   // MFMA-write -> VALU-read hazard
    #pragma unroll
    for (int rt = 0; rt < 2; ++rt)
    #pragma unroll
    for (int ct = 0; ct < 4; ++ct)
    #pragma unroll
    for (int j = 0; j < 4; ++j) {
        int rloc = w*32 + rt*16 + ((l >> 4) << 2) + j;
        if (STORE_GLOBAL) {
            int rg = rbase + rloc;
            if (rg < n)
                dstg[(size_t)rg * HID + (ct << 4) + (l & 15)] = f2b(acc[rt][ct][j]);
        } else {
            gld[rloc][(ct << 4) + (l & 15)] = f2b(fmaxf(acc[rt][ct][j], 0.f));
        }
    }
}

__global__ __launch_bounds__(256) void node_mlp_mfma(
    const ushort* __restrict__ x16,
    const float* __restrict__ W1, const float* __restrict__ b1,
    const float* __restrict__ W2, const float* __restrict__ b2,
    const float* __restrict__ A12,
    const float* __restrict__ ab,
    ushort* __restrict__ u, ushort* __restrict__ v, int n)
{
    __shared__ ushort Wt[4][64][68];
    __shared__ ushort gld[128][68];
    int tid = threadIdx.x;
    int l = tid & 63, w = tid >> 6;
    int rbase = blockIdx.x * 128;

    const float* Wsrc[4] = { W1, A12, W2, A12 + HID*HID };
    for (int m = 0; m < 4; ++m) {
        const float4* s4 = reinterpret_cast<const float4*>(Wsrc[m]);
        #pragma unroll
        for (int q = 0; q < 4; ++q) {
            float4 t = s4[tid*4 + q];
            int idx = tid*16 + q*4;
            int k = idx >> 6, c = idx & 63;
            Wt[m][c+0][k] = f2b(t.x); Wt[m][c+1][k] = f2b(t.y);
            Wt[m][c+2][k] = f2b(t.z); Wt[m][c+3][k] = f2b(t.w);
        }
    }

    s16x4 afr[2][4];
    #pragma unroll
    for (int rt = 0; rt < 2; ++rt) {
        int r = rbase + w*32 + rt*16 + (l & 15);
        int rc = min(r, n - 1);
        const ushort* xr = x16 + (size_t)rc * HID + ((l >> 4) << 2);
        #pragma unroll
        for (int kc = 0; kc < 4; ++kc)
            afr[rt][kc] = *(const s16x4*)(xr + (kc << 4));
    }
    __syncthreads();

    mfma_stage<true,  false>(afr, Wt[0], b1,      gld, w, l, nullptr, rbase, n);
    mfma_stage<false, true >(afr, Wt[1], ab,      gld, w, l, u,       rbase, n);
    mfma_stage<true,  false>(afr, Wt[2], b2,      gld, w, l, nullptr, rbase, n);
    mfma_stage<false, true >(afr, Wt[3], nullptr, gld, w, l, v,       rbase, n);
}

// ---------------------------------------------------------------------------
// CSR build: hist -> 2-level scan -> 4B col scatter; row_sorted from ptr
// ---------------------------------------------------------------------------
__global__ __launch_bounds__(256) void hist_kernel(const int* __restrict__ row,
                                                   int* __restrict__ cnt, int E)
{
    int e = blockIdx.x * 256 + threadIdx.x;
    if (e < E) atomicAdd(&cnt[row[e]], 1);
}

__global__ __launch_bounds__(SCAN_B) void scan1_kernel(const int* __restrict__ cnt,
                                                       int* __restrict__ ptr,
                                                       int* __restrict__ bsum, int n)
{
    __shared__ int lds[SCAN_B];
    int i = blockIdx.x * SCAN_B + threadIdx.x;
    int vin = (i < n) ? cnt[i] : 0;
    int val = vin;
    lds[threadIdx.x] = val;
    __syncthreads();
    for (int off = 1; off < SCAN_B; off <<= 1) {
        int t = (threadIdx.x >= off) ? lds[threadIdx.x - off] : 0;
        __syncthreads();
        val += t;
        lds[threadIdx.x] = val;
        __syncthreads();
    }
    if (i < n) ptr[i] = val - vin;
    if (threadIdx.x == SCAN_B - 1) bsum[blockIdx.x] = val;
}

__global__ __launch_bounds__(1024) void scan2_kernel(const int* __restrict__ bsum,
                                                     int* __restrict__ boffs, int nb)
{
    __shared__ int lds[1024];
    int i = threadIdx.x;
    int vin = (i < nb) ? bsum[i] : 0;
    int val = vin;
    lds[i] = val;
    __syncthreads();
    for (int off = 1; off < 1024; off <<= 1) {
        int t = (i >= off) ? lds[i - off] : 0;
        __syncthreads();
        val += t;
        lds[i] = val;
        __syncthreads();
    }
    if (i < nb) boffs[i] = val - vin;
}

__global__ __launch_bounds__(SCAN_B) void scan3_kernel(int* __restrict__ ptr,
                                                       const int* __restrict__ boffs,
                                                       int n, int E)
{
    int i = blockIdx.x * SCAN_B + threadIdx.x;
    if (i < n) ptr[i] += boffs[blockIdx.x];
    if (i == 0) ptr[n] = E;
}

// 4B-payload scatter: per-row cursors (low contention), col only
__global__ __launch_bounds__(256) void scatter_kernel(const int* __restrict__ row,
                                                      const int* __restrict__ col,
                                                      int* __restrict__ wpos,
                                                      int* __restrict__ col_sorted, int E)
{
    int e = blockIdx.x * 256 + threadIdx.x;
    if (e >= E) return;
    int r = row[e];
    int pos = atomicAdd(&wpos[r], 1);
    col_sorted[pos] = col[e];
}

// row_sorted[ptr[i]..ptr[i+1]) = i  (sequential coalesced-ish writes)
__global__ __launch_bounds__(256) void expand_row(const int* __restrict__ ptr,
                                                  int* __restrict__ row_sorted, int n)
{
    int i = blockIdx.x * 256 + threadIdx.x;
    if (i >= n) return;
    int s = ptr[i], e = ptr[i + 1];
    for (int p = s; p < e; ++p) row_sorted[p] = i;
}

// ---------------------------------------------------------------------------
// Edge mask: 16 lanes per edge (rows sorted -> u gathers are L1/L2-hot)
// ---------------------------------------------------------------------------
__global__ __launch_bounds__(256) void edge_mask16(
    const ushort* __restrict__ u, const ushort* __restrict__ v,
    const float* __restrict__ w2, const float* __restrict__ b2p,
    const int* __restrict__ rows, const int* __restrict__ cols,
    float* __restrict__ mask_sorted, int E)
{
    int g = (blockIdx.x * 256 + threadIdx.x) >> 4;
    if (g >= E) return;
    int sub = threadIdx.x & 15;
    int r = rows[g], c = cols[g];
    ushort4 uu = *reinterpret_cast<const ushort4*>(u + (size_t)r * HID + sub * 4);
    ushort4 vv = *reinterpret_cast<const ushort4*>(v + (size_t)c * HID + sub * 4);
    float4 ww = *reinterpret_cast<const float4*>(w2 + sub * 4);
    float p = fmaxf(b2f(uu.x) + b2f(vv.x), 0.f) * ww.x;
    p = fmaf(fmaxf(b2f(uu.y) + b2f(vv.y), 0.f), ww.y, p);
    p = fmaf(fmaxf(b2f(uu.z) + b2f(vv.z), 0.f), ww.z, p);
    p = fmaf(fmaxf(b2f(uu.w) + b2f(vv.w), 0.f), ww.w, p);
    p += __shfl_xor(p, 1, 64);
    p += __shfl_xor(p, 2, 64);
    p += __shfl_xor(p, 4, 64);
    p += __shfl_xor(p, 8, 64);
    if (sub == 0) {
        float la = p + b2p[0];
        float s = 1.f / (1.f + __expf(-la));
        mask_sorted[g] = fminf(fmaxf(fmaf(s, 1.5f, -0.45f), 0.f), 1.f);
    }
}

__global__ __launch_bounds__(256) void rowsum_dinv(
    const float* __restrict__ mask_sorted, const int* __restrict__ ptr,
    float* __restrict__ dinv, int n)
{
    int i = blockIdx.x * 256 + threadIdx.x;
    if (i >= n) return;
    int s0 = ptr[i], s1 = ptr[i + 1];
    float s = 1e-6f;
    for (int e = s0; e < s1; ++e) s += mask_sorted[e];
    float d = 1.f / sqrtf(s);
    dinv[i] = fminf(d, 10.f);
}

// ---------------------------------------------------------------------------
// Aggregation: wave-per-node, bf16 x gather, f32 accumulate.
// Inner loop software-pipelined 4-deep for gather ILP.
// ---------------------------------------------------------------------------
__global__ __launch_bounds__(256) void agg_csr(
    const ushort* __restrict__ x16,
    const float* __restrict__ mask_sorted, const float* __restrict__ dinv,
    const int* __restrict__ ptr, const int* __restrict__ col_sorted,
    const float* __restrict__ base_in, float* __restrict__ out,
    ushort* __restrict__ x16_out, int n)
{
    int wid = (blockIdx.x * 256 + threadIdx.x) >> 6;
    if (wid >= n) return;
    int lane = threadIdx.x & 63;
    int start = ptr[wid], end = ptr[wid + 1];
    int deg = end - start;
    float acc = 0.f;
    for (int base = 0; base < deg; base += 64) {
        int mcnt = min(64, deg - base);
        int cc = 0; float wv = 0.f;
        if (lane < mcnt) {
            cc = col_sorted[start + base + lane];
            wv = mask_sorted[start + base + lane] * dinv[cc];
        }
        int j = 0;
        for (; j + 4 <= mcnt; j += 4) {
            int   c0 = __shfl(cc, j,     64);
            int   c1 = __shfl(cc, j + 1, 64);
            int   c2 = __shfl(cc, j + 2, 64);
            int   c3 = __shfl(cc, j + 3, 64);
            float w0 = __shfl(wv, j,     64);
            float w1 = __shfl(wv, j + 1, 64);
            float w2 = __shfl(wv, j + 2, 64);
            float w3 = __shfl(wv, j + 3, 64);
            float x0 = b2f(x16[(size_t)c0 * HID + lane]);
            float x1 = b2f(x16[(size_t)c1 * HID + lane]);
            float x2 = b2f(x16[(size_t)c2 * HID + lane]);
            float x3 = b2f(x16[(size_t)c3 * HID + lane]);
            acc = fmaf(w0, x0, acc);
            acc = fmaf(w1, x1, acc);
            acc = fmaf(w2, x2, acc);
            acc = fmaf(w3, x3, acc);
        }
        for (; j < mcnt; ++j) {
            int c = __shfl(cc, j, 64);
            float wj = __shfl(wv, j, 64);
            acc = fmaf(wj, b2f(x16[(size_t)c * HID + lane]), acc);
        }
    }
    float res = acc * dinv[wid];
    size_t o = (size_t)wid * HID + lane;
    out[o] = base_in[o] + res;
    x16_out[o] = f2b(res);
}

// ---------------------------------------------------------------------------

extern "C" void kernel_launch(void* const* d_in, const int* in_sizes, int n_in,
                              void* d_out, int out_size, void* d_ws, size_t ws_size,
                              hipStream_t stream)
{
    const float* feat  = (const float*)d_in[0];
    const float* nbW   = (const float*)d_in[1];
    const float* nbb   = (const float*)d_in[2];
    const float* selfW = (const float*)d_in[3];
    const float* selfb = (const float*)d_in[4];
    const float* a1W   = (const float*)d_in[5];
    const float* a1b   = (const float*)d_in[6];
    const float* a2W   = (const float*)d_in[7];
    const float* a2b   = (const float*)d_in[8];
    const int*   row   = (const int*)d_in[9];
    const int*   col   = (const int*)d_in[10];
    float* out = (float*)d_out;

    const int n = in_sizes[0] / HID;
    const int E = in_sizes[9];
    const int L = in_sizes[1] / (HID * HID);
    const size_t NH = (size_t)n * HID;

    char* p = (char*)d_ws;
    ushort* u          = (ushort*)p; p += NH * 2;
    ushort* v          = (ushort*)p; p += NH * 2;
    ushort* x16a       = (ushort*)p; p += NH * 2;
    ushort* x16b       = (ushort*)p; p += NH * 2;
    float* dinv        = (float*)p;  p += (size_t)n * 4;
    float* mask_sorted = (float*)p;  p += (size_t)E * 4;
    int*   col_sorted  = (int*)p;    p += (size_t)E * 4;
    int*   row_sorted  = (int*)p;    p += (size_t)E * 4;
    int*   ptr         = (int*)p;    p += (size_t)(n + 1) * 4;
    int*   cnt         = (int*)p;    p += (size_t)n * 4;
    int*   bsum        = (int*)p;    p += 1024 * 4;
    int*   boffs       = (int*)p;    p += 1024 * 4;

    const int eBlocks = (E + 255) / 256;
    const int sBlocks = (n + SCAN_B - 1) / SCAN_B;
    const int wBlocks = (int)(((size_t)n * 64 + 255) / 256);
    const int mBlocks = (E + 15) / 16;
    const int nodeBlocks = (n + 127) / 128;

    // CSR build (once per call)
    hipMemsetAsync(cnt, 0, (size_t)n * sizeof(int), stream);
    hist_kernel<<<eBlocks, 256, 0, stream>>>(row, cnt, E);
    scan1_kernel<<<sBlocks, SCAN_B, 0, stream>>>(cnt, ptr, bsum, n);
    scan2_kernel<<<1, 1024, 0, stream>>>(bsum, boffs, sBlocks);
    scan3_kernel<<<sBlocks, SCAN_B, 0, stream>>>(ptr, boffs, n, E);
    hipMemcpyAsync(cnt, ptr, (size_t)n * sizeof(int), hipMemcpyDeviceToDevice, stream);
    scatter_kernel<<<eBlocks, 256, 0, stream>>>(row, col, cnt, col_sorted, E);
    expand_row<<<(n + 255) / 256, 256, 0, stream>>>(ptr, row_sorted, n);

    // feat -> bf16 (layer-0 x)
    cvt_bf16_kernel<<<(int)((NH / 8 + 255) / 256), 256, 0, stream>>>(feat, x16a, (long)(NH / 8));

    const ushort* x_in = x16a;
    ushort* x_out = x16b;
    for (int l = 0; l < L; ++l) {
        node_mlp_mfma<<<nodeBlocks, 256, 0, stream>>>(
            x_in,
            nbW + (size_t)l * HID * HID,   nbb + (size_t)l * HID,
            selfW + (size_t)l * HID * HID, selfb + (size_t)l * HID,
            a1W + (size_t)l * 2 * HID * HID,
            a1b + (size_t)l * HID,
            u, v, n);

        edge_mask16<<<mBlocks, 256, 0, stream>>>(
            u, v, a2W + (size_t)l * HID, a2b + l,
            row_sorted, col_sorted, mask_sorted, E);

        rowsum_dinv<<<(n + 255) / 256, 256, 0, stream>>>(mask_sorted, ptr, dinv, n);

        agg_csr<<<wBlocks, 256, 0, stream>>>(
            x_in, mask_sorted, dinv, ptr, col_sorted,
            (l == 0) ? feat : out, out, x_out, n);

        ushort* t = (ushort*)x_in;
        x_in = x_out;
        x_out = (l == 0) ? x16a : t;
    }
}

// Round 8
// 457.639 us; speedup vs baseline: 1.9113x; 1.2314x over previous
//
#include <hip/hip_runtime.h>
#include <hip/hip_bf16.h>
#include <math.h>

#define HID 64
#define BK 8                      // 256 rows per bucket
#define B_WG 256                  // partition workgroups
#define KMAX 512

typedef __attribute__((ext_vector_type(4))) float f32x4;
typedef __attribute__((ext_vector_type(4))) short s16x4;

__device__ __forceinline__ ushort f2b(float x) {
    __hip_bfloat16 h = __float2bfloat16(x);
    return *reinterpret_cast<ushort*>(&h);
}
__device__ __forceinline__ float b2f(ushort u) {
    return __uint_as_float(((unsigned)u) << 16);
}

// D = A*B + C, 16x16x16 bf16 MFMA. s_nop covers VALU-write -> MFMA-read hazard.
__device__ __forceinline__ f32x4 mfma16(s16x4 a, s16x4 b, f32x4 c) {
    asm("s_nop 1\n\tv_mfma_f32_16x16x16_bf16 %0, %1, %2, %0"
        : "+v"(c) : "v"(a), "v"(b));
    return c;
}

// ---------------------------------------------------------------------------
// feat (f32) -> bf16 copy, 8 elems/thread
// ---------------------------------------------------------------------------
__global__ __launch_bounds__(256) void cvt_bf16_kernel(const float* __restrict__ x,
                                                       ushort* __restrict__ x16, long n8)
{
    long i = (long)blockIdx.x * 256 + threadIdx.x;
    if (i >= n8) return;
    const float4* s = reinterpret_cast<const float4*>(x) + i * 2;
    float4 a = s[0], b = s[1];
    union { uint4 q; ushort s[8]; } pk;
    pk.s[0] = f2b(a.x); pk.s[1] = f2b(a.y); pk.s[2] = f2b(a.z); pk.s[3] = f2b(a.w);
    pk.s[4] = f2b(b.x); pk.s[5] = f2b(b.y); pk.s[6] = f2b(b.z); pk.s[7] = f2b(b.w);
    reinterpret_cast<uint4*>(x16)[i] = pk.q;
}

// ---------------------------------------------------------------------------
// MFMA node MLP. Block = 256 thr (4 waves), M-tile = 128 nodes.
// ---------------------------------------------------------------------------
template<bool A_FROM_REGS, bool STORE_GLOBAL>
__device__ __forceinline__ void mfma_stage(
    const s16x4 afr[2][4], const ushort (*Wt)[68], const float* bias,
    ushort (*gld)[68], int w, int l, ushort* dstg, int rbase, int n)
{
    f32x4 acc[2][4];
    #pragma unroll
    for (int ct = 0; ct < 4; ++ct) {
        float bv = bias ? bias[(ct << 4) + (l & 15)] : 0.f;
        acc[0][ct] = (f32x4){bv, bv, bv, bv};
        acc[1][ct] = (f32x4){bv, bv, bv, bv};
    }
    #pragma unroll
    for (int kc = 0; kc < 4; ++kc) {
        s16x4 a0, a1;
        if (A_FROM_REGS) {
            a0 = afr[0][kc]; a1 = afr[1][kc];
        } else {
            a0 = *(const s16x4*)&gld[w*32 +  0 + (l & 15)][((l >> 4) << 2) + (kc << 4)];
            a1 = *(const s16x4*)&gld[w*32 + 16 + (l & 15)][((l >> 4) << 2) + (kc << 4)];
        }
        #pragma unroll
        for (int ct = 0; ct < 4; ++ct) {
            s16x4 b = *(const s16x4*)&Wt[(ct << 4) + (l & 15)][((l >> 4) << 2) + (kc << 4)];
            acc[0][ct] = mfma16(a0, b, acc[0][ct]);
            acc[1][ct] = mfma16(a1, b, acc[1][ct]);
        }
    }
    asm volatile("s_nop 7\n\ts_nop 7");   // MFMA-write -> VALU-read hazard
    #pragma unroll
    for (int rt = 0; rt < 2; ++rt)
    #pragma unroll
    for (int ct = 0; ct < 4; ++ct)
    #pragma unroll
    for (int j = 0; j < 4; ++j) {
        int rloc = w*32 + rt*16 + ((l >> 4) << 2) + j;
        if (STORE_GLOBAL) {
            int rg = rbase + rloc;
            if (rg < n)
                dstg[(size_t)rg * HID + (ct << 4) + (l & 15)] = f2b(acc[rt][ct][j]);
        } else {
            gld[rloc][(ct << 4) + (l & 15)] = f2b(fmaxf(acc[rt][ct][j], 0.f));
        }
    }
}

__global__ __launch_bounds__(256) void node_mlp_mfma(
    const ushort* __restrict__ x16,
    const float* __restrict__ W1, const float* __restrict__ b1,
    const float* __restrict__ W2, const float* __restrict__ b2,
    const float* __restrict__ A12,
    const float* __restrict__ ab,
    ushort* __restrict__ u, ushort* __restrict__ v, int n)
{
    __shared__ ushort Wt[4][64][68];
    __shared__ ushort gld[128][68];
    int tid = threadIdx.x;
    int l = tid & 63, w = tid >> 6;
    int rbase = blockIdx.x * 128;

    const float* Wsrc[4] = { W1, A12, W2, A12 + HID*HID };
    for (int m = 0; m < 4; ++m) {
        const float4* s4 = reinterpret_cast<const float4*>(Wsrc[m]);
        #pragma unroll
        for (int q = 0; q < 4; ++q) {
            float4 t = s4[tid*4 + q];
            int idx = tid*16 + q*4;
            int k = idx >> 6, c = idx & 63;
            Wt[m][c+0][k] = f2b(t.x); Wt[m][c+1][k] = f2b(t.y);
            Wt[m][c+2][k] = f2b(t.z); Wt[m][c+3][k] = f2b(t.w);
        }
    }

    s16x4 afr[2][4];
    #pragma unroll
    for (int rt = 0; rt < 2; ++rt) {
        int r = rbase + w*32 + rt*16 + (l & 15);
        int rc = min(r, n - 1);
        const ushort* xr = x16 + (size_t)rc * HID + ((l >> 4) << 2);
        #pragma unroll
        for (int kc = 0; kc < 4; ++kc)
            afr[rt][kc] = *(const s16x4*)(xr + (kc << 4));
    }
    __syncthreads();

    mfma_stage<true,  false>(afr, Wt[0], b1,      gld, w, l, nullptr, rbase, n);
    mfma_stage<false, true >(afr, Wt[1], ab,      gld, w, l, u,       rbase, n);
    mfma_stage<true,  false>(afr, Wt[2], b2,      gld, w, l, nullptr, rbase, n);
    mfma_stage<false, true >(afr, Wt[3], nullptr, gld, w, l, v,       rbase, n);
}

// ---------------------------------------------------------------------------
// CSR build, radix style: no global atomics, exclusive write segments.
// bucket = row >> BK (256 rows/bucket). hist layout: hist[b * B_WG + w].
// ---------------------------------------------------------------------------
__global__ __launch_bounds__(256) void bucket_hist(const int* __restrict__ row,
                                                   int* __restrict__ hist,
                                                   int E, int K, int chunk)
{
    __shared__ int h[KMAX];
    for (int i = threadIdx.x; i < K; i += 256) h[i] = 0;
    __syncthreads();
    int w = blockIdx.x;
    int s = w * chunk, e = min(E, s + chunk);
    for (int i = s + threadIdx.x; i < e; i += 256)
        atomicAdd(&h[row[i] >> BK], 1);
    __syncthreads();
    for (int i = threadIdx.x; i < K; i += 256)
        hist[i * B_WG + w] = h[i];
}

// single block: per-bucket totals -> exclusive scan -> bbase[0..K]; ptr[n]=E
__global__ __launch_bounds__(512) void bucket_base(const int* __restrict__ hist,
                                                   int* __restrict__ bbase,
                                                   int* __restrict__ ptr,
                                                   int K, int E, int n)
{
    __shared__ int lds[512];
    int t = threadIdx.x;
    int total = 0;
    if (t < K) {
        const int* hrow = hist + t * B_WG;
        for (int w = 0; w < B_WG; ++w) total += hrow[w];
    }
    lds[t] = total;
    __syncthreads();
    int val = total;
    for (int off = 1; off < 512; off <<= 1) {
        int tmp = (t >= off) ? lds[t - off] : 0;
        __syncthreads();
        val += tmp;
        lds[t] = val;
        __syncthreads();
    }
    if (t <= K) bbase[t] = val - total;   // t==K: total=0 -> bbase[K]=E
    if (t == 0) ptr[n] = E;
}

// per-bucket scan over workgroups -> exclusive segment start offs[b*B_WG+w]
__global__ __launch_bounds__(B_WG) void wg_offsets(const int* __restrict__ hist,
                                                   const int* __restrict__ bbase,
                                                   int* __restrict__ offs)
{
    __shared__ int lds[B_WG];
    int b = blockIdx.x, t = threadIdx.x;
    int v = hist[b * B_WG + t];
    lds[t] = v;
    __syncthreads();
    int val = v;
    for (int off = 1; off < B_WG; off <<= 1) {
        int tmp = (t >= off) ? lds[t - off] : 0;
        __syncthreads();
        val += tmp;
        lds[t] = val;
        __syncthreads();
    }
    offs[b * B_WG + t] = bbase[b] + val - v;
}

// partition: each wg writes (r,c) into its exclusive per-bucket segments
__global__ __launch_bounds__(256) void partition_edges(const int* __restrict__ row,
                                                       const int* __restrict__ col,
                                                       const int* __restrict__ offs,
                                                       int2* __restrict__ tmp,
                                                       int E, int K, int chunk)
{
    __shared__ int cur[KMAX];
    int w = blockIdx.x;
    for (int i = threadIdx.x; i < K; i += 256)
        cur[i] = offs[i * B_WG + w];
    __syncthreads();
    int s = w * chunk, e = min(E, s + chunk);
    for (int i = s + threadIdx.x; i < e; i += 256) {
        int r = row[i], c = col[i];
        int pos = atomicAdd(&cur[r >> BK], 1);
        tmp[pos] = make_int2(r, c);
    }
}

// fine sort within bucket: row-histogram + scan -> ptr slice + row/col scatter
__global__ __launch_bounds__(256) void fine_sort(const int2* __restrict__ tmp,
                                                 const int* __restrict__ bbase,
                                                 int* __restrict__ ptr,
                                                 int* __restrict__ row_sorted,
                                                 int* __restrict__ col_sorted,
                                                 int n)
{
    __shared__ int rcnt[256];
    __shared__ int scan[256];
    __shared__ int cur[256];
    int b = blockIdx.x, t = threadIdx.x;
    int row0 = b << BK;
    rcnt[t] = 0;
    __syncthreads();
    int s = bbase[b], e = bbase[b + 1];
    for (int i = s + t; i < e; i += 256)
        atomicAdd(&rcnt[tmp[i].x & 255], 1);
    __syncthreads();
    int v = rcnt[t];
    scan[t] = v;
    __syncthreads();
    int val = v;
    for (int off = 1; off < 256; off <<= 1) {
        int tm = (t >= off) ? scan[t - off] : 0;
        __syncthreads();
        val += tm;
        scan[t] = val;
        __syncthreads();
    }
    int rstart = s + val - v;
    int r = row0 + t;
    if (r < n) ptr[r] = rstart;
    cur[t] = rstart;
    __syncthreads();
    for (int i = s + t; i < e; i += 256) {
        int2 rc = tmp[i];
        int pos = atomicAdd(&cur[rc.x & 255], 1);
        row_sorted[pos] = rc.x;
        col_sorted[pos] = rc.y;
    }
}

// ---------------------------------------------------------------------------
// Edge mask: 16 lanes per edge (rows sorted -> u gathers are L1/L2-hot)
// ---------------------------------------------------------------------------
__global__ __launch_bounds__(256) void edge_mask16(
    const ushort* __restrict__ u, const ushort* __restrict__ v,
    const float* __restrict__ w2, const float* __restrict__ b2p,
    const int* __restrict__ rows, const int* __restrict__ cols,
    float* __restrict__ mask_sorted, int E)
{
    int g = (blockIdx.x * 256 + threadIdx.x) >> 4;
    if (g >= E) return;
    int sub = threadIdx.x & 15;
    int r = rows[g], c = cols[g];
    ushort4 uu = *reinterpret_cast<const ushort4*>(u + (size_t)r * HID + sub * 4);
    ushort4 vv = *reinterpret_cast<const ushort4*>(v + (size_t)c * HID + sub * 4);
    float4 ww = *reinterpret_cast<const float4*>(w2 + sub * 4);
    float p = fmaxf(b2f(uu.x) + b2f(vv.x), 0.f) * ww.x;
    p = fmaf(fmaxf(b2f(uu.y) + b2f(vv.y), 0.f), ww.y, p);
    p = fmaf(fmaxf(b2f(uu.z) + b2f(vv.z), 0.f), ww.z, p);
    p = fmaf(fmaxf(b2f(uu.w) + b2f(vv.w), 0.f), ww.w, p);
    p += __shfl_xor(p, 1, 64);
    p += __shfl_xor(p, 2, 64);
    p += __shfl_xor(p, 4, 64);
    p += __shfl_xor(p, 8, 64);
    if (sub == 0) {
        float la = p + b2p[0];
        float s = 1.f / (1.f + __expf(-la));
        mask_sorted[g] = fminf(fmaxf(fmaf(s, 1.5f, -0.45f), 0.f), 1.f);
    }
}

__global__ __launch_bounds__(256) void rowsum_dinv(
    const float* __restrict__ mask_sorted, const int* __restrict__ ptr,
    float* __restrict__ dinv, int n)
{
    int i = blockIdx.x * 256 + threadIdx.x;
    if (i >= n) return;
    int s0 = ptr[i], s1 = ptr[i + 1];
    float s = 1e-6f;
    for (int e = s0; e < s1; ++e) s += mask_sorted[e];
    float d = 1.f / sqrtf(s);
    dinv[i] = fminf(d, 10.f);
}

// ---------------------------------------------------------------------------
// Aggregation: wave-per-node, bf16 x gather, f32 accumulate, 4-deep ILP.
// ---------------------------------------------------------------------------
__global__ __launch_bounds__(256) void agg_csr(
    const ushort* __restrict__ x16,
    const float* __restrict__ mask_sorted, const float* __restrict__ dinv,
    const int* __restrict__ ptr, const int* __restrict__ col_sorted,
    const float* __restrict__ base_in, float* __restrict__ out,
    ushort* __restrict__ x16_out, int n)
{
    int wid = (blockIdx.x * 256 + threadIdx.x) >> 6;
    if (wid >= n) return;
    int lane = threadIdx.x & 63;
    int start = ptr[wid], end = ptr[wid + 1];
    int deg = end - start;
    float acc = 0.f;
    for (int base = 0; base < deg; base += 64) {
        int mcnt = min(64, deg - base);
        int cc = 0; float wv = 0.f;
        if (lane < mcnt) {
            cc = col_sorted[start + base + lane];
            wv = mask_sorted[start + base + lane] * dinv[cc];
        }
        int j = 0;
        for (; j + 4 <= mcnt; j += 4) {
            int   c0 = __shfl(cc, j,     64);
            int   c1 = __shfl(cc, j + 1, 64);
            int   c2 = __shfl(cc, j + 2, 64);
            int   c3 = __shfl(cc, j + 3, 64);
            float w0 = __shfl(wv, j,     64);
            float w1 = __shfl(wv, j + 1, 64);
            float w2 = __shfl(wv, j + 2, 64);
            float w3 = __shfl(wv, j + 3, 64);
            float x0 = b2f(x16[(size_t)c0 * HID + lane]);
            float x1 = b2f(x16[(size_t)c1 * HID + lane]);
            float x2 = b2f(x16[(size_t)c2 * HID + lane]);
            float x3 = b2f(x16[(size_t)c3 * HID + lane]);
            acc = fmaf(w0, x0, acc);
            acc = fmaf(w1, x1, acc);
            acc = fmaf(w2, x2, acc);
            acc = fmaf(w3, x3, acc);
        }
        for (; j < mcnt; ++j) {
            int c = __shfl(cc, j, 64);
            float wj = __shfl(wv, j, 64);
            acc = fmaf(wj, b2f(x16[(size_t)c * HID + lane]), acc);
        }
    }
    float res = acc * dinv[wid];
    size_t o = (size_t)wid * HID + lane;
    out[o] = base_in[o] + res;
    x16_out[o] = f2b(res);
}

// ---------------------------------------------------------------------------

extern "C" void kernel_launch(void* const* d_in, const int* in_sizes, int n_in,
                              void* d_out, int out_size, void* d_ws, size_t ws_size,
                              hipStream_t stream)
{
    const float* feat  = (const float*)d_in[0];
    const float* nbW   = (const float*)d_in[1];
    const float* nbb   = (const float*)d_in[2];
    const float* selfW = (const float*)d_in[3];
    const float* selfb = (const float*)d_in[4];
    const float* a1W   = (const float*)d_in[5];
    const float* a1b   = (const float*)d_in[6];
    const float* a2W   = (const float*)d_in[7];
    const float* a2b   = (const float*)d_in[8];
    const int*   row   = (const int*)d_in[9];
    const int*   col   = (const int*)d_in[10];
    float* out = (float*)d_out;

    const int n = in_sizes[0] / HID;
    const int E = in_sizes[9];
    const int L = in_sizes[1] / (HID * HID);
    const size_t NH = (size_t)n * HID;
    const int K = (n + 255) >> BK;            // buckets of 256 rows (<= KMAX)
    const int chunk = (E + B_WG - 1) / B_WG;

    char* p = (char*)d_ws;
    ushort* u          = (ushort*)p; p += NH * 2;
    ushort* v          = (ushort*)p; p += NH * 2;
    ushort* x16a       = (ushort*)p; p += NH * 2;
    ushort* x16b       = (ushort*)p; p += NH * 2;
    float* dinv        = (float*)p;  p += (size_t)n * 4;
    float* mask_sorted = (float*)p;  p += (size_t)E * 4;
    int*   col_sorted  = (int*)p;    p += (size_t)E * 4;
    int*   row_sorted  = (int*)p;    p += (size_t)E * 4;
    int2*  tmp_rc      = (int2*)p;   p += (size_t)E * 8;
    int*   ptr         = (int*)p;    p += (size_t)(n + 1) * 4;
    int*   hist        = (int*)p;    p += (size_t)KMAX * B_WG * 4;
    int*   offs        = (int*)p;    p += (size_t)KMAX * B_WG * 4;
    int*   bbase       = (int*)p;    p += 1024 * 4;

    const int wBlocks = (int)(((size_t)n * 64 + 255) / 256);
    const int mBlocks = (E + 15) / 16;
    const int nodeBlocks = (n + 127) / 128;

    // ---- CSR build: radix partition, no global atomics ----
    bucket_hist<<<B_WG, 256, 0, stream>>>(row, hist, E, K, chunk);
    bucket_base<<<1, 512, 0, stream>>>(hist, bbase, ptr, K, E, n);
    wg_offsets<<<K, B_WG, 0, stream>>>(hist, bbase, offs);
    partition_edges<<<B_WG, 256, 0, stream>>>(row, col, offs, tmp_rc, E, K, chunk);
    fine_sort<<<K, 256, 0, stream>>>(tmp_rc, bbase, ptr, row_sorted, col_sorted, n);

    // feat -> bf16 (layer-0 x)
    cvt_bf16_kernel<<<(int)((NH / 8 + 255) / 256), 256, 0, stream>>>(feat, x16a, (long)(NH / 8));

    const ushort* x_in = x16a;
    ushort* x_out = x16b;
    for (int l = 0; l < L; ++l) {
        node_mlp_mfma<<<nodeBlocks, 256, 0, stream>>>(
            x_in,
            nbW + (size_t)l * HID * HID,   nbb + (size_t)l * HID,
            selfW + (size_t)l * HID * HID, selfb + (size_t)l * HID,
            a1W + (size_t)l * 2 * HID * HID,
            a1b + (size_t)l * HID,
            u, v, n);

        edge_mask16<<<mBlocks, 256, 0, stream>>>(
            u, v, a2W + (size_t)l * HID, a2b + l,
            row_sorted, col_sorted, mask_sorted, E);

        rowsum_dinv<<<(n + 255) / 256, 256, 0, stream>>>(mask_sorted, ptr, dinv, n);

        agg_csr<<<wBlocks, 256, 0, stream>>>(
            x_in, mask_sorted, dinv, ptr, col_sorted,
            (l == 0) ? feat : out, out, x_out, n);

        ushort* t = (ushort*)x_in;
        x_in = x_out;
        x_out = (l == 0) ? x16a : t;
    }
}

// Round 9
// 365.960 us; speedup vs baseline: 2.3901x; 1.2505x over previous
//
#include <hip/hip_runtime.h>
#include <hip/hip_bf16.h>
#include <math.h>

#define HID 64
#define BK 8                      // 256 rows per bucket
#define B_WG 256                  // partition workgroups
#define KMAX 512

typedef __attribute__((ext_vector_type(4))) float f32x4;
typedef __attribute__((ext_vector_type(4))) short s16x4;

__device__ __forceinline__ ushort f2b(float x) {
    __hip_bfloat16 h = __float2bfloat16(x);
    return *reinterpret_cast<ushort*>(&h);
}
__device__ __forceinline__ float b2f(ushort u) {
    return __uint_as_float(((unsigned)u) << 16);
}

// D = A*B + C, 16x16x16 bf16 MFMA. s_nop covers VALU-write -> MFMA-read hazard.
__device__ __forceinline__ f32x4 mfma16(s16x4 a, s16x4 b, f32x4 c) {
    asm("s_nop 1\n\tv_mfma_f32_16x16x16_bf16 %0, %1, %2, %0"
        : "+v"(c) : "v"(a), "v"(b));
    return c;
}

// ---------------------------------------------------------------------------
// feat (f32) -> bf16 copy, 8 elems/thread
// ---------------------------------------------------------------------------
__global__ __launch_bounds__(256) void cvt_bf16_kernel(const float* __restrict__ x,
                                                       ushort* __restrict__ x16, long n8)
{
    long i = (long)blockIdx.x * 256 + threadIdx.x;
    if (i >= n8) return;
    const float4* s = reinterpret_cast<const float4*>(x) + i * 2;
    float4 a = s[0], b = s[1];
    union { uint4 q; ushort s[8]; } pk;
    pk.s[0] = f2b(a.x); pk.s[1] = f2b(a.y); pk.s[2] = f2b(a.z); pk.s[3] = f2b(a.w);
    pk.s[4] = f2b(b.x); pk.s[5] = f2b(b.y); pk.s[6] = f2b(b.z); pk.s[7] = f2b(b.w);
    reinterpret_cast<uint4*>(x16)[i] = pk.q;
}

// ---------------------------------------------------------------------------
// MFMA node MLP. Block = 256 thr (4 waves), M-tile = 128 nodes.
// ---------------------------------------------------------------------------
template<bool A_FROM_REGS, bool STORE_GLOBAL>
__device__ __forceinline__ void mfma_stage(
    const s16x4 afr[2][4], const ushort (*Wt)[68], const float* bias,
    ushort (*gld)[68], int w, int l, ushort* dstg, int rbase, int n)
{
    f32x4 acc[2][4];
    #pragma unroll
    for (int ct = 0; ct < 4; ++ct) {
        float bv = bias ? bias[(ct << 4) + (l & 15)] : 0.f;
        acc[0][ct] = (f32x4){bv, bv, bv, bv};
        acc[1][ct] = (f32x4){bv, bv, bv, bv};
    }
    #pragma unroll
    for (int kc = 0; kc < 4; ++kc) {
        s16x4 a0, a1;
        if (A_FROM_REGS) {
            a0 = afr[0][kc]; a1 = afr[1][kc];
        } else {
            a0 = *(const s16x4*)&gld[w*32 +  0 + (l & 15)][((l >> 4) << 2) + (kc << 4)];
            a1 = *(const s16x4*)&gld[w*32 + 16 + (l & 15)][((l >> 4) << 2) + (kc << 4)];
        }
        #pragma unroll
        for (int ct = 0; ct < 4; ++ct) {
            s16x4 b = *(const s16x4*)&Wt[(ct << 4) + (l & 15)][((l >> 4) << 2) + (kc << 4)];
            acc[0][ct] = mfma16(a0, b, acc[0][ct]);
            acc[1][ct] = mfma16(a1, b, acc[1][ct]);
        }
    }
    asm volatile("s_nop 7\n\ts_nop 7");   // MFMA-write -> VALU-read hazard
    #pragma unroll
    for (int rt = 0; rt < 2; ++rt)
    #pragma unroll
    for (int ct = 0; ct < 4; ++ct)
    #pragma unroll
    for (int j = 0; j < 4; ++j) {
        int rloc = w*32 + rt*16 + ((l >> 4) << 2) + j;
        if (STORE_GLOBAL) {
            int rg = rbase + rloc;
            if (rg < n)
                dstg[(size_t)rg * HID + (ct << 4) + (l & 15)] = f2b(acc[rt][ct][j]);
        } else {
            gld[rloc][(ct << 4) + (l & 15)] = f2b(fmaxf(acc[rt][ct][j], 0.f));
        }
    }
}

__global__ __launch_bounds__(256) void node_mlp_mfma(
    const ushort* __restrict__ x16,
    const float* __restrict__ W1, const float* __restrict__ b1,
    const float* __restrict__ W2, const float* __restrict__ b2,
    const float* __restrict__ A12,
    const float* __restrict__ ab,
    ushort* __restrict__ u, ushort* __restrict__ v, int n)
{
    __shared__ ushort Wt[4][64][68];
    __shared__ ushort gld[128][68];
    int tid = threadIdx.x;
    int l = tid & 63, w = tid >> 6;
    int rbase = blockIdx.x * 128;

    const float* Wsrc[4] = { W1, A12, W2, A12 + HID*HID };
    for (int m = 0; m < 4; ++m) {
        const float4* s4 = reinterpret_cast<const float4*>(Wsrc[m]);
        #pragma unroll
        for (int q = 0; q < 4; ++q) {
            float4 t = s4[tid*4 + q];
            int idx = tid*16 + q*4;
            int k = idx >> 6, c = idx & 63;
            Wt[m][c+0][k] = f2b(t.x); Wt[m][c+1][k] = f2b(t.y);
            Wt[m][c+2][k] = f2b(t.z); Wt[m][c+3][k] = f2b(t.w);
        }
    }

    s16x4 afr[2][4];
    #pragma unroll
    for (int rt = 0; rt < 2; ++rt) {
        int r = rbase + w*32 + rt*16 + (l & 15);
        int rc = min(r, n - 1);
        const ushort* xr = x16 + (size_t)rc * HID + ((l >> 4) << 2);
        #pragma unroll
        for (int kc = 0; kc < 4; ++kc)
            afr[rt][kc] = *(const s16x4*)(xr + (kc << 4));
    }
    __syncthreads();

    mfma_stage<true,  false>(afr, Wt[0], b1,      gld, w, l, nullptr, rbase, n);
    mfma_stage<false, true >(afr, Wt[1], ab,      gld, w, l, u,       rbase, n);
    mfma_stage<true,  false>(afr, Wt[2], b2,      gld, w, l, nullptr, rbase, n);
    mfma_stage<false, true >(afr, Wt[3], nullptr, gld, w, l, v,       rbase, n);
}

// ---------------------------------------------------------------------------
// CSR build, radix style: no global atomics, exclusive write segments.
// ---------------------------------------------------------------------------
__global__ __launch_bounds__(256) void bucket_hist(const int* __restrict__ row,
                                                   int* __restrict__ hist,
                                                   int E, int K, int chunk)
{
    __shared__ int h[KMAX];
    for (int i = threadIdx.x; i < K; i += 256) h[i] = 0;
    __syncthreads();
    int w = blockIdx.x;
    int s = w * chunk, e = min(E, s + chunk);
    for (int i = s + threadIdx.x; i < e; i += 256)
        atomicAdd(&h[row[i] >> BK], 1);
    __syncthreads();
    for (int i = threadIdx.x; i < K; i += 256)
        hist[i * B_WG + w] = h[i];
}

__global__ __launch_bounds__(512) void bucket_base(const int* __restrict__ hist,
                                                   int* __restrict__ bbase,
                                                   int* __restrict__ ptr,
                                                   int K, int E, int n)
{
    __shared__ int lds[512];
    int t = threadIdx.x;
    int total = 0;
    if (t < K) {
        const int* hrow = hist + t * B_WG;
        for (int w = 0; w < B_WG; ++w) total += hrow[w];
    }
    lds[t] = total;
    __syncthreads();
    int val = total;
    for (int off = 1; off < 512; off <<= 1) {
        int tmp = (t >= off) ? lds[t - off] : 0;
        __syncthreads();
        val += tmp;
        lds[t] = val;
        __syncthreads();
    }
    if (t <= K) bbase[t] = val - total;
    if (t == 0) ptr[n] = E;
}

__global__ __launch_bounds__(B_WG) void wg_offsets(const int* __restrict__ hist,
                                                   const int* __restrict__ bbase,
                                                   int* __restrict__ offs)
{
    __shared__ int lds[B_WG];
    int b = blockIdx.x, t = threadIdx.x;
    int v = hist[b * B_WG + t];
    lds[t] = v;
    __syncthreads();
    int val = v;
    for (int off = 1; off < B_WG; off <<= 1) {
        int tmp = (t >= off) ? lds[t - off] : 0;
        __syncthreads();
        val += tmp;
        lds[t] = val;
        __syncthreads();
    }
    offs[b * B_WG + t] = bbase[b] + val - v;
}

__global__ __launch_bounds__(256) void partition_edges(const int* __restrict__ row,
                                                       const int* __restrict__ col,
                                                       const int* __restrict__ offs,
                                                       int2* __restrict__ tmp,
                                                       int E, int K, int chunk)
{
    __shared__ int cur[KMAX];
    int w = blockIdx.x;
    for (int i = threadIdx.x; i < K; i += 256)
        cur[i] = offs[i * B_WG + w];
    __syncthreads();
    int s = w * chunk, e = min(E, s + chunk);
    for (int i = s + threadIdx.x; i < e; i += 256) {
        int r = row[i], c = col[i];
        int pos = atomicAdd(&cur[r >> BK], 1);
        tmp[pos] = make_int2(r, c);
    }
}

__global__ __launch_bounds__(256) void fine_sort(const int2* __restrict__ tmp,
                                                 const int* __restrict__ bbase,
                                                 int* __restrict__ ptr,
                                                 int* __restrict__ row_sorted,
                                                 int* __restrict__ col_sorted,
                                                 int n)
{
    __shared__ int rcnt[256];
    __shared__ int scan[256];
    __shared__ int cur[256];
    int b = blockIdx.x, t = threadIdx.x;
    int row0 = b << BK;
    rcnt[t] = 0;
    __syncthreads();
    int s = bbase[b], e = bbase[b + 1];
    for (int i = s + t; i < e; i += 256)
        atomicAdd(&rcnt[tmp[i].x & 255], 1);
    __syncthreads();
    int v = rcnt[t];
    scan[t] = v;
    __syncthreads();
    int val = v;
    for (int off = 1; off < 256; off <<= 1) {
        int tm = (t >= off) ? scan[t - off] : 0;
        __syncthreads();
        val += tm;
        scan[t] = val;
        __syncthreads();
    }
    int rstart = s + val - v;
    int r = row0 + t;
    if (r < n) ptr[r] = rstart;
    cur[t] = rstart;
    __syncthreads();
    for (int i = s + t; i < e; i += 256) {
        int2 rc = tmp[i];
        int pos = atomicAdd(&cur[rc.x & 255], 1);
        row_sorted[pos] = rc.x;
        col_sorted[pos] = rc.y;
    }
}

// ---------------------------------------------------------------------------
// Edge mask: 8 lanes per edge, ushort8 (16B) loads, 3-stage reduce
// ---------------------------------------------------------------------------
__global__ __launch_bounds__(256) void edge_mask8(
    const ushort* __restrict__ u, const ushort* __restrict__ v,
    const float* __restrict__ w2, const float* __restrict__ b2p,
    const int* __restrict__ rows, const int* __restrict__ cols,
    float* __restrict__ mask_sorted, int E)
{
    int g = (blockIdx.x * 256 + threadIdx.x) >> 3;
    if (g >= E) return;
    int sub = threadIdx.x & 7;
    int r = rows[g], c = cols[g];
    union { uint4 q; ushort s[8]; } uu, vv;
    uu.q = *reinterpret_cast<const uint4*>(u + (size_t)r * HID + sub * 8);
    vv.q = *reinterpret_cast<const uint4*>(v + (size_t)c * HID + sub * 8);
    float4 wa = *reinterpret_cast<const float4*>(w2 + sub * 8);
    float4 wb = *reinterpret_cast<const float4*>(w2 + sub * 8 + 4);
    float p;
    p =        fmaxf(b2f(uu.s[0]) + b2f(vv.s[0]), 0.f) * wa.x;
    p = fmaf(fmaxf(b2f(uu.s[1]) + b2f(vv.s[1]), 0.f), wa.y, p);
    p = fmaf(fmaxf(b2f(uu.s[2]) + b2f(vv.s[2]), 0.f), wa.z, p);
    p = fmaf(fmaxf(b2f(uu.s[3]) + b2f(vv.s[3]), 0.f), wa.w, p);
    p = fmaf(fmaxf(b2f(uu.s[4]) + b2f(vv.s[4]), 0.f), wb.x, p);
    p = fmaf(fmaxf(b2f(uu.s[5]) + b2f(vv.s[5]), 0.f), wb.y, p);
    p = fmaf(fmaxf(b2f(uu.s[6]) + b2f(vv.s[6]), 0.f), wb.z, p);
    p = fmaf(fmaxf(b2f(uu.s[7]) + b2f(vv.s[7]), 0.f), wb.w, p);
    p += __shfl_xor(p, 1, 64);
    p += __shfl_xor(p, 2, 64);
    p += __shfl_xor(p, 4, 64);
    if (sub == 0) {
        float la = p + b2p[0];
        float s = 1.f / (1.f + __expf(-la));
        mask_sorted[g] = fminf(fmaxf(fmaf(s, 1.5f, -0.45f), 0.f), 1.f);
    }
}

__global__ __launch_bounds__(256) void rowsum_dinv(
    const float* __restrict__ mask_sorted, const int* __restrict__ ptr,
    float* __restrict__ dinv, int n)
{
    int i = blockIdx.x * 256 + threadIdx.x;
    if (i >= n) return;
    int s0 = ptr[i], s1 = ptr[i + 1];
    float s = 1e-6f;
    for (int e = s0; e < s1; ++e) s += mask_sorted[e];
    float d = 1.f / sqrtf(s);
    dinv[i] = fminf(d, 10.f);
}

// ---------------------------------------------------------------------------
// Aggregation: wave-per-node, TWO cols per iteration.
// lane = 32*half + d2; each lane loads ushort2 (2 dims) of col j+half.
// acc is float2 (2 dims); halves combined at the end via shfl_xor(32).
// ---------------------------------------------------------------------------
__global__ __launch_bounds__(256) void agg_csr2(
    const ushort* __restrict__ x16,
    const float* __restrict__ mask_sorted, const float* __restrict__ dinv,
    const int* __restrict__ ptr, const int* __restrict__ col_sorted,
    const float* __restrict__ base_in, float* __restrict__ out,
    ushort* __restrict__ x16_out, int n)
{
    int wid = (blockIdx.x * 256 + threadIdx.x) >> 6;
    if (wid >= n) return;
    int lane = threadIdx.x & 63;
    int half = lane >> 5;        // 0: even cols, 1: odd cols
    int d2 = lane & 31;          // dim pair index
    int start = ptr[wid], end = ptr[wid + 1];
    int deg = end - start;
    float ax = 0.f, ay = 0.f;

    for (int base = 0; base < deg; base += 64) {
        int mcnt = min(64, deg - base);
        int cc = 0; float wv = 0.f;
        if (lane < mcnt) {
            cc = col_sorted[start + base + lane];
            wv = mask_sorted[start + base + lane] * dinv[cc];
        }
        int j = 0;
        for (; j + 8 <= mcnt; j += 8) {
            int jj = j + half;
            int   c0 = __shfl(cc, jj,     64);
            int   c1 = __shfl(cc, jj + 2, 64);
            int   c2 = __shfl(cc, jj + 4, 64);
            int   c3 = __shfl(cc, jj + 6, 64);
            float w0 = __shfl(wv, jj,     64);
            float w1 = __shfl(wv, jj + 2, 64);
            float w2 = __shfl(wv, jj + 4, 64);
            float w3 = __shfl(wv, jj + 6, 64);
            uint p0 = *reinterpret_cast<const uint*>(x16 + (size_t)c0 * HID + d2 * 2);
            uint p1 = *reinterpret_cast<const uint*>(x16 + (size_t)c1 * HID + d2 * 2);
            uint p2 = *reinterpret_cast<const uint*>(x16 + (size_t)c2 * HID + d2 * 2);
            uint p3 = *reinterpret_cast<const uint*>(x16 + (size_t)c3 * HID + d2 * 2);
            ax = fmaf(w0, b2f((ushort)p0), ax); ay = fmaf(w0, b2f((ushort)(p0 >> 16)), ay);
            ax = fmaf(w1, b2f((ushort)p1), ax); ay = fmaf(w1, b2f((ushort)(p1 >> 16)), ay);
            ax = fmaf(w2, b2f((ushort)p2), ax); ay = fmaf(w2, b2f((ushort)(p2 >> 16)), ay);
            ax = fmaf(w3, b2f((ushort)p3), ax); ay = fmaf(w3, b2f((ushort)(p3 >> 16)), ay);
        }
        for (; j < mcnt; j += 2) {
            int jj = j + half;               // jj <= mcnt; lanes >= mcnt hold wv=0,cc=0
            int   c0 = __shfl(cc, jj, 64);
            float w0 = __shfl(wv, jj, 64);
            uint p0 = *reinterpret_cast<const uint*>(x16 + (size_t)c0 * HID + d2 * 2);
            ax = fmaf(w0, b2f((ushort)p0), ax);
            ay = fmaf(w0, b2f((ushort)(p0 >> 16)), ay);
        }
    }
    // combine even/odd halves
    ax += __shfl_xor(ax, 32, 64);
    ay += __shfl_xor(ay, 32, 64);
    if (half == 0) {
        float dv = dinv[wid];
        float rx = ax * dv, ry = ay * dv;
        size_t o2 = (size_t)wid * 32 + d2;
        float2 b = reinterpret_cast<const float2*>(base_in)[o2];
        float2 ov; ov.x = b.x + rx; ov.y = b.y + ry;
        reinterpret_cast<float2*>(out)[o2] = ov;
        uint pk = (uint)f2b(rx) | ((uint)f2b(ry) << 16);
        reinterpret_cast<uint*>(x16_out)[o2] = pk;
    }
}

// ---------------------------------------------------------------------------

extern "C" void kernel_launch(void* const* d_in, const int* in_sizes, int n_in,
                              void* d_out, int out_size, void* d_ws, size_t ws_size,
                              hipStream_t stream)
{
    const float* feat  = (const float*)d_in[0];
    const float* nbW   = (const float*)d_in[1];
    const float* nbb   = (const float*)d_in[2];
    const float* selfW = (const float*)d_in[3];
    const float* selfb = (const float*)d_in[4];
    const float* a1W   = (const float*)d_in[5];
    const float* a1b   = (const float*)d_in[6];
    const float* a2W   = (const float*)d_in[7];
    const float* a2b   = (const float*)d_in[8];
    const int*   row   = (const int*)d_in[9];
    const int*   col   = (const int*)d_in[10];
    float* out = (float*)d_out;

    const int n = in_sizes[0] / HID;
    const int E = in_sizes[9];
    const int L = in_sizes[1] / (HID * HID);
    const size_t NH = (size_t)n * HID;
    const int K = (n + 255) >> BK;
    const int chunk = (E + B_WG - 1) / B_WG;

    char* p = (char*)d_ws;
    ushort* u          = (ushort*)p; p += NH * 2;
    ushort* v          = (ushort*)p; p += NH * 2;
    ushort* x16a       = (ushort*)p; p += NH * 2;
    ushort* x16b       = (ushort*)p; p += NH * 2;
    float* dinv        = (float*)p;  p += (size_t)n * 4;
    float* mask_sorted = (float*)p;  p += (size_t)E * 4;
    int*   col_sorted  = (int*)p;    p += (size_t)E * 4;
    int*   row_sorted  = (int*)p;    p += (size_t)E * 4;
    int2*  tmp_rc      = (int2*)p;   p += (size_t)E * 8;
    int*   ptr         = (int*)p;    p += (size_t)(n + 1) * 4;
    int*   hist        = (int*)p;    p += (size_t)KMAX * B_WG * 4;
    int*   offs        = (int*)p;    p += (size_t)KMAX * B_WG * 4;
    int*   bbase       = (int*)p;    p += 1024 * 4;

    const int wBlocks = (int)(((size_t)n * 64 + 255) / 256);
    const int mBlocks = (E + 31) / 32;
    const int nodeBlocks = (n + 127) / 128;

    // ---- CSR build: radix partition, no global atomics ----
    bucket_hist<<<B_WG, 256, 0, stream>>>(row, hist, E, K, chunk);
    bucket_base<<<1, 512, 0, stream>>>(hist, bbase, ptr, K, E, n);
    wg_offsets<<<K, B_WG, 0, stream>>>(hist, bbase, offs);
    partition_edges<<<B_WG, 256, 0, stream>>>(row, col, offs, tmp_rc, E, K, chunk);
    fine_sort<<<K, 256, 0, stream>>>(tmp_rc, bbase, ptr, row_sorted, col_sorted, n);

    // feat -> bf16 (layer-0 x)
    cvt_bf16_kernel<<<(int)((NH / 8 + 255) / 256), 256, 0, stream>>>(feat, x16a, (long)(NH / 8));

    const ushort* x_in = x16a;
    ushort* x_out = x16b;
    for (int l = 0; l < L; ++l) {
        node_mlp_mfma<<<nodeBlocks, 256, 0, stream>>>(
            x_in,
            nbW + (size_t)l * HID * HID,   nbb + (size_t)l * HID,
            selfW + (size_t)l * HID * HID, selfb + (size_t)l * HID,
            a1W + (size_t)l * 2 * HID * HID,
            a1b + (size_t)l * HID,
            u, v, n);

        edge_mask8<<<mBlocks, 256, 0, stream>>>(
            u, v, a2W + (size_t)l * HID, a2b + l,
            row_sorted, col_sorted, mask_sorted, E);

        rowsum_dinv<<<(n + 255) / 256, 256, 0, stream>>>(mask_sorted, ptr, dinv, n);

        agg_csr2<<<wBlocks, 256, 0, stream>>>(
            x_in, mask_sorted, dinv, ptr, col_sorted,
            (l == 0) ? feat : out, out, x_out, n);

        ushort* t = (ushort*)x_in;
        x_in = x_out;
        x_out = (l == 0) ? x16a : t;
    }
}

// Round 10
// 357.353 us; speedup vs baseline: 2.4477x; 1.0241x over previous
//
#include <hip/hip_runtime.h>
#include <hip/hip_bf16.h>
#include <math.h>

#define HID 64
#define BK 8                      // 256 rows per bucket
#define B_WG 256                  // partition workgroups
#define KMAX 512

typedef __attribute__((ext_vector_type(4))) float f32x4;
typedef __attribute__((ext_vector_type(4))) short s16x4;

__device__ __forceinline__ ushort f2b(float x) {
    __hip_bfloat16 h = __float2bfloat16(x);
    return *reinterpret_cast<ushort*>(&h);
}
__device__ __forceinline__ float b2f(ushort u) {
    return __uint_as_float(((unsigned)u) << 16);
}

// D = A*B + C, 16x16x16 bf16 MFMA. s_nop covers VALU-write -> MFMA-read hazard.
__device__ __forceinline__ f32x4 mfma16(s16x4 a, s16x4 b, f32x4 c) {
    asm("s_nop 1\n\tv_mfma_f32_16x16x16_bf16 %0, %1, %2, %0"
        : "+v"(c) : "v"(a), "v"(b));
    return c;
}

// ---------------------------------------------------------------------------
// feat (f32) -> bf16 copy, 8 elems/thread
// ---------------------------------------------------------------------------
__global__ __launch_bounds__(256) void cvt_bf16_kernel(const float* __restrict__ x,
                                                       ushort* __restrict__ x16, long n8)
{
    long i = (long)blockIdx.x * 256 + threadIdx.x;
    if (i >= n8) return;
    const float4* s = reinterpret_cast<const float4*>(x) + i * 2;
    float4 a = s[0], b = s[1];
    union { uint4 q; ushort s[8]; } pk;
    pk.s[0] = f2b(a.x); pk.s[1] = f2b(a.y); pk.s[2] = f2b(a.z); pk.s[3] = f2b(a.w);
    pk.s[4] = f2b(b.x); pk.s[5] = f2b(b.y); pk.s[6] = f2b(b.z); pk.s[7] = f2b(b.w);
    reinterpret_cast<uint4*>(x16)[i] = pk.q;
}

// out = feat + r1 + r2 + r3 (res buffers are bf16), 8 elems/thread
__global__ __launch_bounds__(256) void final_combine(
    const float* __restrict__ feat,
    const ushort* __restrict__ r1, const ushort* __restrict__ r2,
    const ushort* __restrict__ r3, float* __restrict__ out, long n8)
{
    long i = (long)blockIdx.x * 256 + threadIdx.x;
    if (i >= n8) return;
    const float4* f4 = reinterpret_cast<const float4*>(feat) + i * 2;
    float4 a = f4[0], b = f4[1];
    union { uint4 q; ushort s[8]; } q1, q2, q3;
    q1.q = reinterpret_cast<const uint4*>(r1)[i];
    q2.q = reinterpret_cast<const uint4*>(r2)[i];
    q3.q = reinterpret_cast<const uint4*>(r3)[i];
    float4 o0, o1;
    o0.x = a.x + b2f(q1.s[0]) + b2f(q2.s[0]) + b2f(q3.s[0]);
    o0.y = a.y + b2f(q1.s[1]) + b2f(q2.s[1]) + b2f(q3.s[1]);
    o0.z = a.z + b2f(q1.s[2]) + b2f(q2.s[2]) + b2f(q3.s[2]);
    o0.w = a.w + b2f(q1.s[3]) + b2f(q2.s[3]) + b2f(q3.s[3]);
    o1.x = b.x + b2f(q1.s[4]) + b2f(q2.s[4]) + b2f(q3.s[4]);
    o1.y = b.y + b2f(q1.s[5]) + b2f(q2.s[5]) + b2f(q3.s[5]);
    o1.z = b.z + b2f(q1.s[6]) + b2f(q2.s[6]) + b2f(q3.s[6]);
    o1.w = b.w + b2f(q1.s[7]) + b2f(q2.s[7]) + b2f(q3.s[7]);
    float4* d4 = reinterpret_cast<float4*>(out) + i * 2;
    d4[0] = o0; d4[1] = o1;
}

// ---------------------------------------------------------------------------
// MFMA node MLP. Block = 256 thr (4 waves), M-tile = 128 nodes.
// ---------------------------------------------------------------------------
template<bool A_FROM_REGS, bool STORE_GLOBAL>
__device__ __forceinline__ void mfma_stage(
    const s16x4 afr[2][4], const ushort (*Wt)[68], const float* bias,
    ushort (*gld)[68], int w, int l, ushort* dstg, int rbase, int n)
{
    f32x4 acc[2][4];
    #pragma unroll
    for (int ct = 0; ct < 4; ++ct) {
        float bv = bias ? bias[(ct << 4) + (l & 15)] : 0.f;
        acc[0][ct] = (f32x4){bv, bv, bv, bv};
        acc[1][ct] = (f32x4){bv, bv, bv, bv};
    }
    #pragma unroll
    for (int kc = 0; kc < 4; ++kc) {
        s16x4 a0, a1;
        if (A_FROM_REGS) {
            a0 = afr[0][kc]; a1 = afr[1][kc];
        } else {
            a0 = *(const s16x4*)&gld[w*32 +  0 + (l & 15)][((l >> 4) << 2) + (kc << 4)];
            a1 = *(const s16x4*)&gld[w*32 + 16 + (l & 15)][((l >> 4) << 2) + (kc << 4)];
        }
        #pragma unroll
        for (int ct = 0; ct < 4; ++ct) {
            s16x4 b = *(const s16x4*)&Wt[(ct << 4) + (l & 15)][((l >> 4) << 2) + (kc << 4)];
            acc[0][ct] = mfma16(a0, b, acc[0][ct]);
            acc[1][ct] = mfma16(a1, b, acc[1][ct]);
        }
    }
    asm volatile("s_nop 7\n\ts_nop 7");   // MFMA-write -> VALU-read hazard
    #pragma unroll
    for (int rt = 0; rt < 2; ++rt)
    #pragma unroll
    for (int ct = 0; ct < 4; ++ct)
    #pragma unroll
    for (int j = 0; j < 4; ++j) {
        int rloc = w*32 + rt*16 + ((l >> 4) << 2) + j;
        if (STORE_GLOBAL) {
            int rg = rbase + rloc;
            if (rg < n)
                dstg[(size_t)rg * HID + (ct << 4) + (l & 15)] = f2b(acc[rt][ct][j]);
        } else {
            gld[rloc][(ct << 4) + (l & 15)] = f2b(fmaxf(acc[rt][ct][j], 0.f));
        }
    }
}

__global__ __launch_bounds__(256) void node_mlp_mfma(
    const ushort* __restrict__ x16,
    const float* __restrict__ W1, const float* __restrict__ b1,
    const float* __restrict__ W2, const float* __restrict__ b2,
    const float* __restrict__ A12,
    const float* __restrict__ ab,
    ushort* __restrict__ u, ushort* __restrict__ v, int n)
{
    __shared__ ushort Wt[4][64][68];
    __shared__ ushort gld[128][68];
    int tid = threadIdx.x;
    int l = tid & 63, w = tid >> 6;
    int rbase = blockIdx.x * 128;

    const float* Wsrc[4] = { W1, A12, W2, A12 + HID*HID };
    for (int m = 0; m < 4; ++m) {
        const float4* s4 = reinterpret_cast<const float4*>(Wsrc[m]);
        #pragma unroll
        for (int q = 0; q < 4; ++q) {
            float4 t = s4[tid*4 + q];
            int idx = tid*16 + q*4;
            int k = idx >> 6, c = idx & 63;
            Wt[m][c+0][k] = f2b(t.x); Wt[m][c+1][k] = f2b(t.y);
            Wt[m][c+2][k] = f2b(t.z); Wt[m][c+3][k] = f2b(t.w);
        }
    }

    s16x4 afr[2][4];
    #pragma unroll
    for (int rt = 0; rt < 2; ++rt) {
        int r = rbase + w*32 + rt*16 + (l & 15);
        int rc = min(r, n - 1);
        const ushort* xr = x16 + (size_t)rc * HID + ((l >> 4) << 2);
        #pragma unroll
        for (int kc = 0; kc < 4; ++kc)
            afr[rt][kc] = *(const s16x4*)(xr + (kc << 4));
    }
    __syncthreads();

    mfma_stage<true,  false>(afr, Wt[0], b1,      gld, w, l, nullptr, rbase, n);
    mfma_stage<false, true >(afr, Wt[1], ab,      gld, w, l, u,       rbase, n);
    mfma_stage<true,  false>(afr, Wt[2], b2,      gld, w, l, nullptr, rbase, n);
    mfma_stage<false, true >(afr, Wt[3], nullptr, gld, w, l, v,       rbase, n);
}

// ---------------------------------------------------------------------------
// CSR build, radix style: no global atomics, exclusive write segments.
// ---------------------------------------------------------------------------
__global__ __launch_bounds__(256) void bucket_hist(const int* __restrict__ row,
                                                   int* __restrict__ hist,
                                                   int E, int K, int chunk)
{
    __shared__ int h[KMAX];
    for (int i = threadIdx.x; i < K; i += 256) h[i] = 0;
    __syncthreads();
    int w = blockIdx.x;
    int s = w * chunk, e = min(E, s + chunk);
    for (int i = s + threadIdx.x; i < e; i += 256)
        atomicAdd(&h[row[i] >> BK], 1);
    __syncthreads();
    for (int i = threadIdx.x; i < K; i += 256)
        hist[i * B_WG + w] = h[i];
}

__global__ __launch_bounds__(512) void bucket_base(const int* __restrict__ hist,
                                                   int* __restrict__ bbase,
                                                   int* __restrict__ ptr,
                                                   int K, int E, int n)
{
    __shared__ int lds[512];
    int t = threadIdx.x;
    int total = 0;
    if (t < K) {
        const int* hrow = hist + t * B_WG;
        for (int w = 0; w < B_WG; ++w) total += hrow[w];
    }
    lds[t] = total;
    __syncthreads();
    int val = total;
    for (int off = 1; off < 512; off <<= 1) {
        int tmp = (t >= off) ? lds[t - off] : 0;
        __syncthreads();
        val += tmp;
        lds[t] = val;
        __syncthreads();
    }
    if (t <= K) bbase[t] = val - total;
    if (t == 0) ptr[n] = E;
}

__global__ __launch_bounds__(B_WG) void wg_offsets(const int* __restrict__ hist,
                                                   const int* __restrict__ bbase,
                                                   int* __restrict__ offs)
{
    __shared__ int lds[B_WG];
    int b = blockIdx.x, t = threadIdx.x;
    int v = hist[b * B_WG + t];
    lds[t] = v;
    __syncthreads();
    int val = v;
    for (int off = 1; off < B_WG; off <<= 1) {
        int tmp = (t >= off) ? lds[t - off] : 0;
        __syncthreads();
        val += tmp;
        lds[t] = val;
        __syncthreads();
    }
    offs[b * B_WG + t] = bbase[b] + val - v;
}

__global__ __launch_bounds__(256) void partition_edges(const int* __restrict__ row,
                                                       const int* __restrict__ col,
                                                       const int* __restrict__ offs,
                                                       int2* __restrict__ tmp,
                                                       int E, int K, int chunk)
{
    __shared__ int cur[KMAX];
    int w = blockIdx.x;
    for (int i = threadIdx.x; i < K; i += 256)
        cur[i] = offs[i * B_WG + w];
    __syncthreads();
    int s = w * chunk, e = min(E, s + chunk);
    for (int i = s + threadIdx.x; i < e; i += 256) {
        int r = row[i], c = col[i];
        int pos = atomicAdd(&cur[r >> BK], 1);
        tmp[pos] = make_int2(r, c);
    }
}

__global__ __launch_bounds__(256) void fine_sort(const int2* __restrict__ tmp,
                                                 const int* __restrict__ bbase,
                                                 int* __restrict__ ptr,
                                                 int* __restrict__ row_sorted,
                                                 int* __restrict__ col_sorted,
                                                 int n)
{
    __shared__ int rcnt[256];
    __shared__ int scan[256];
    __shared__ int cur[256];
    int b = blockIdx.x, t = threadIdx.x;
    int row0 = b << BK;
    rcnt[t] = 0;
    __syncthreads();
    int s = bbase[b], e = bbase[b + 1];
    for (int i = s + t; i < e; i += 256)
        atomicAdd(&rcnt[tmp[i].x & 255], 1);
    __syncthreads();
    int v = rcnt[t];
    scan[t] = v;
    __syncthreads();
    int val = v;
    for (int off = 1; off < 256; off <<= 1) {
        int tm = (t >= off) ? scan[t - off] : 0;
        __syncthreads();
        val += tm;
        scan[t] = val;
        __syncthreads();
    }
    int rstart = s + val - v;
    int r = row0 + t;
    if (r < n) ptr[r] = rstart;
    cur[t] = rstart;
    __syncthreads();
    for (int i = s + t; i < e; i += 256) {
        int2 rc = tmp[i];
        int pos = atomicAdd(&cur[rc.x & 255], 1);
        row_sorted[pos] = rc.x;
        col_sorted[pos] = rc.y;
    }
}

// ---------------------------------------------------------------------------
// Edge mask: 8 lanes per edge, ushort8 (16B) loads, 3-stage reduce
// ---------------------------------------------------------------------------
__global__ __launch_bounds__(256) void edge_mask8(
    const ushort* __restrict__ u, const ushort* __restrict__ v,
    const float* __restrict__ w2, const float* __restrict__ b2p,
    const int* __restrict__ rows, const int* __restrict__ cols,
    float* __restrict__ mask_sorted, int E)
{
    int g = (blockIdx.x * 256 + threadIdx.x) >> 3;
    if (g >= E) return;
    int sub = threadIdx.x & 7;
    int r = rows[g], c = cols[g];
    union { uint4 q; ushort s[8]; } uu, vv;
    uu.q = *reinterpret_cast<const uint4*>(u + (size_t)r * HID + sub * 8);
    vv.q = *reinterpret_cast<const uint4*>(v + (size_t)c * HID + sub * 8);
    float4 wa = *reinterpret_cast<const float4*>(w2 + sub * 8);
    float4 wb = *reinterpret_cast<const float4*>(w2 + sub * 8 + 4);
    float p;
    p =        fmaxf(b2f(uu.s[0]) + b2f(vv.s[0]), 0.f) * wa.x;
    p = fmaf(fmaxf(b2f(uu.s[1]) + b2f(vv.s[1]), 0.f), wa.y, p);
    p = fmaf(fmaxf(b2f(uu.s[2]) + b2f(vv.s[2]), 0.f), wa.z, p);
    p = fmaf(fmaxf(b2f(uu.s[3]) + b2f(vv.s[3]), 0.f), wa.w, p);
    p = fmaf(fmaxf(b2f(uu.s[4]) + b2f(vv.s[4]), 0.f), wb.x, p);
    p = fmaf(fmaxf(b2f(uu.s[5]) + b2f(vv.s[5]), 0.f), wb.y, p);
    p = fmaf(fmaxf(b2f(uu.s[6]) + b2f(vv.s[6]), 0.f), wb.z, p);
    p = fmaf(fmaxf(b2f(uu.s[7]) + b2f(vv.s[7]), 0.f), wb.w, p);
    p += __shfl_xor(p, 1, 64);
    p += __shfl_xor(p, 2, 64);
    p += __shfl_xor(p, 4, 64);
    if (sub == 0) {
        float la = p + b2p[0];
        float s = 1.f / (1.f + __expf(-la));
        mask_sorted[g] = fminf(fmaxf(fmaf(s, 1.5f, -0.45f), 0.f), 1.f);
    }
}

__global__ __launch_bounds__(256) void rowsum_dinv(
    const float* __restrict__ mask_sorted, const int* __restrict__ ptr,
    float* __restrict__ dinv, int n)
{
    int i = blockIdx.x * 256 + threadIdx.x;
    if (i >= n) return;
    int s0 = ptr[i], s1 = ptr[i + 1];
    float s = 1e-6f;
    for (int e = s0; e < s1; ++e) s += mask_sorted[e];
    float d = 1.f / sqrtf(s);
    dinv[i] = fminf(d, 10.f);
}

// ---------------------------------------------------------------------------
// Aggregation: wave-per-node, TWO cols per iteration, tail-free (zero-padded).
// lane = 32*half + d2; each lane loads ushort2 (2 dims) of col j+half.
// Inactive lanes hold cc=0, wv=0 -> padded gathers hit node 0's L1-hot lines
// and contribute 0. Writes res (bf16) only; out combined in a final pass.
// ---------------------------------------------------------------------------
__global__ __launch_bounds__(256) void agg_csr2(
    const ushort* __restrict__ x16,
    const float* __restrict__ mask_sorted, const float* __restrict__ dinv,
    const int* __restrict__ ptr, const int* __restrict__ col_sorted,
    ushort* __restrict__ x16_out, int n)
{
    int wid = (blockIdx.x * 256 + threadIdx.x) >> 6;
    if (wid >= n) return;
    int lane = threadIdx.x & 63;
    int half = lane >> 5;        // 0: even cols, 1: odd cols
    int d2 = lane & 31;          // dim pair index
    int start = ptr[wid], end = ptr[wid + 1];
    int deg = end - start;
    float ax = 0.f, ay = 0.f;

    for (int base = 0; base < deg; base += 64) {
        int mcnt = min(64, deg - base);
        int cc = 0; float wv = 0.f;
        if (lane < mcnt) {
            cc = col_sorted[start + base + lane];
            wv = mask_sorted[start + base + lane] * dinv[cc];
        }
        int m8 = (mcnt + 7) & ~7;           // round up; padded lanes give w=0
        for (int j = 0; j < m8; j += 8) {
            int jj = j + half;
            int   c0 = __shfl(cc, jj,     64);
            int   c1 = __shfl(cc, jj + 2, 64);
            int   c2 = __shfl(cc, jj + 4, 64);
            int   c3 = __shfl(cc, jj + 6, 64);
            float w0 = __shfl(wv, jj,     64);
            float w1 = __shfl(wv, jj + 2, 64);
            float w2 = __shfl(wv, jj + 4, 64);
            float w3 = __shfl(wv, jj + 6, 64);
            uint p0 = *reinterpret_cast<const uint*>(x16 + (size_t)c0 * HID + d2 * 2);
            uint p1 = *reinterpret_cast<const uint*>(x16 + (size_t)c1 * HID + d2 * 2);
            uint p2 = *reinterpret_cast<const uint*>(x16 + (size_t)c2 * HID + d2 * 2);
            uint p3 = *reinterpret_cast<const uint*>(x16 + (size_t)c3 * HID + d2 * 2);
            ax = fmaf(w0, b2f((ushort)p0), ax); ay = fmaf(w0, b2f((ushort)(p0 >> 16)), ay);
            ax = fmaf(w1, b2f((ushort)p1), ax); ay = fmaf(w1, b2f((ushort)(p1 >> 16)), ay);
            ax = fmaf(w2, b2f((ushort)p2), ax); ay = fmaf(w2, b2f((ushort)(p2 >> 16)), ay);
            ax = fmaf(w3, b2f((ushort)p3), ax); ay = fmaf(w3, b2f((ushort)(p3 >> 16)), ay);
        }
    }
    // combine even/odd halves
    ax += __shfl_xor(ax, 32, 64);
    ay += __shfl_xor(ay, 32, 64);
    if (half == 0) {
        float dv = dinv[wid];
        float rx = ax * dv, ry = ay * dv;
        size_t o2 = (size_t)wid * 32 + d2;
        uint pk = (uint)f2b(rx) | ((uint)f2b(ry) << 16);
        reinterpret_cast<uint*>(x16_out)[o2] = pk;
    }
}

// ---------------------------------------------------------------------------

extern "C" void kernel_launch(void* const* d_in, const int* in_sizes, int n_in,
                              void* d_out, int out_size, void* d_ws, size_t ws_size,
                              hipStream_t stream)
{
    const float* feat  = (const float*)d_in[0];
    const float* nbW   = (const float*)d_in[1];
    const float* nbb   = (const float*)d_in[2];
    const float* selfW = (const float*)d_in[3];
    const float* selfb = (const float*)d_in[4];
    const float* a1W   = (const float*)d_in[5];
    const float* a1b   = (const float*)d_in[6];
    const float* a2W   = (const float*)d_in[7];
    const float* a2b   = (const float*)d_in[8];
    const int*   row   = (const int*)d_in[9];
    const int*   col   = (const int*)d_in[10];
    float* out = (float*)d_out;

    const int n = in_sizes[0] / HID;
    const int E = in_sizes[9];
    const int L = in_sizes[1] / (HID * HID);
    const size_t NH = (size_t)n * HID;
    const int K = (n + 255) >> BK;
    const int chunk = (E + B_WG - 1) / B_WG;

    char* p = (char*)d_ws;
    ushort* u          = (ushort*)p; p += NH * 2;
    ushort* v          = (ushort*)p; p += NH * 2;
    ushort* xf         = (ushort*)p; p += NH * 2;   // bf16(feat)
    ushort* r1         = (ushort*)p; p += NH * 2;   // res layer 1
    ushort* r2         = (ushort*)p; p += NH * 2;   // res layer 2
    ushort* r3         = (ushort*)p; p += NH * 2;   // res layer 3
    float* dinv        = (float*)p;  p += (size_t)n * 4;
    float* mask_sorted = (float*)p;  p += (size_t)E * 4;
    int*   col_sorted  = (int*)p;    p += (size_t)E * 4;
    int*   row_sorted  = (int*)p;    p += (size_t)E * 4;
    int2*  tmp_rc      = (int2*)p;   p += (size_t)E * 8;
    int*   ptr         = (int*)p;    p += (size_t)(n + 1) * 4;
    int*   hist        = (int*)p;    p += (size_t)KMAX * B_WG * 4;
    int*   offs        = (int*)p;    p += (size_t)KMAX * B_WG * 4;
    int*   bbase       = (int*)p;    p += 1024 * 4;

    ushort* res[3] = { r1, r2, r3 };

    const int wBlocks = (int)(((size_t)n * 64 + 255) / 256);
    const int mBlocks = (E + 31) / 32;
    const int nodeBlocks = (n + 127) / 128;

    // ---- CSR build: radix partition, no global atomics ----
    bucket_hist<<<B_WG, 256, 0, stream>>>(row, hist, E, K, chunk);
    bucket_base<<<1, 512, 0, stream>>>(hist, bbase, ptr, K, E, n);
    wg_offsets<<<K, B_WG, 0, stream>>>(hist, bbase, offs);
    partition_edges<<<B_WG, 256, 0, stream>>>(row, col, offs, tmp_rc, E, K, chunk);
    fine_sort<<<K, 256, 0, stream>>>(tmp_rc, bbase, ptr, row_sorted, col_sorted, n);

    // feat -> bf16 (layer-0 x)
    cvt_bf16_kernel<<<(int)((NH / 8 + 255) / 256), 256, 0, stream>>>(feat, xf, (long)(NH / 8));

    const ushort* x_in = xf;
    for (int l = 0; l < L; ++l) {
        node_mlp_mfma<<<nodeBlocks, 256, 0, stream>>>(
            x_in,
            nbW + (size_t)l * HID * HID,   nbb + (size_t)l * HID,
            selfW + (size_t)l * HID * HID, selfb + (size_t)l * HID,
            a1W + (size_t)l * 2 * HID * HID,
            a1b + (size_t)l * HID,
            u, v, n);

        edge_mask8<<<mBlocks, 256, 0, stream>>>(
            u, v, a2W + (size_t)l * HID, a2b + l,
            row_sorted, col_sorted, mask_sorted, E);

        rowsum_dinv<<<(n + 255) / 256, 256, 0, stream>>>(mask_sorted, ptr, dinv, n);

        agg_csr2<<<wBlocks, 256, 0, stream>>>(
            x_in, mask_sorted, dinv, ptr, col_sorted,
            res[min(l, 2)], n);

        x_in = res[min(l, 2)];
    }

    final_combine<<<(int)((NH / 8 + 255) / 256), 256, 0, stream>>>(
        feat, r1, r2, r3, out, (long)(NH / 8));
}

// Round 11
// 340.250 us; speedup vs baseline: 2.5707x; 1.0503x over previous
//
#include <hip/hip_runtime.h>
#include <hip/hip_bf16.h>
#include <math.h>

#define HID 64
#define BK 8                      // 256 rows per bucket
#define B_WG 256                  // partition workgroups
#define KMAX 512

typedef __attribute__((ext_vector_type(4))) float f32x4;
typedef __attribute__((ext_vector_type(4))) short s16x4;

__device__ __forceinline__ ushort f2b(float x) {
    __hip_bfloat16 h = __float2bfloat16(x);
    return *reinterpret_cast<ushort*>(&h);
}
__device__ __forceinline__ float b2f(ushort u) {
    return __uint_as_float(((unsigned)u) << 16);
}

// D = A*B + C, 16x16x16 bf16 MFMA. s_nop covers VALU-write -> MFMA-read hazard.
__device__ __forceinline__ f32x4 mfma16(s16x4 a, s16x4 b, f32x4 c) {
    asm("s_nop 1\n\tv_mfma_f32_16x16x16_bf16 %0, %1, %2, %0"
        : "+v"(c) : "v"(a), "v"(b));
    return c;
}

// ---------------------------------------------------------------------------
// feat (f32) -> bf16 copy, 8 elems/thread
// ---------------------------------------------------------------------------
__global__ __launch_bounds__(256) void cvt_bf16_kernel(const float* __restrict__ x,
                                                       ushort* __restrict__ x16, long n8)
{
    long i = (long)blockIdx.x * 256 + threadIdx.x;
    if (i >= n8) return;
    const float4* s = reinterpret_cast<const float4*>(x) + i * 2;
    float4 a = s[0], b = s[1];
    union { uint4 q; ushort s[8]; } pk;
    pk.s[0] = f2b(a.x); pk.s[1] = f2b(a.y); pk.s[2] = f2b(a.z); pk.s[3] = f2b(a.w);
    pk.s[4] = f2b(b.x); pk.s[5] = f2b(b.y); pk.s[6] = f2b(b.z); pk.s[7] = f2b(b.w);
    reinterpret_cast<uint4*>(x16)[i] = pk.q;
}

// ---------------------------------------------------------------------------
// MFMA node MLP. Block = 256 thr (4 waves), M-tile = 128 nodes.
// ---------------------------------------------------------------------------
template<bool A_FROM_REGS, bool STORE_GLOBAL>
__device__ __forceinline__ void mfma_stage(
    const s16x4 afr[2][4], const ushort (*Wt)[68], const float* bias,
    ushort (*gld)[68], int w, int l, ushort* dstg, int rbase, int n)
{
    f32x4 acc[2][4];
    #pragma unroll
    for (int ct = 0; ct < 4; ++ct) {
        float bv = bias ? bias[(ct << 4) + (l & 15)] : 0.f;
        acc[0][ct] = (f32x4){bv, bv, bv, bv};
        acc[1][ct] = (f32x4){bv, bv, bv, bv};
    }
    #pragma unroll
    for (int kc = 0; kc < 4; ++kc) {
        s16x4 a0, a1;
        if (A_FROM_REGS) {
            a0 = afr[0][kc]; a1 = afr[1][kc];
        } else {
            a0 = *(const s16x4*)&gld[w*32 +  0 + (l & 15)][((l >> 4) << 2) + (kc << 4)];
            a1 = *(const s16x4*)&gld[w*32 + 16 + (l & 15)][((l >> 4) << 2) + (kc << 4)];
        }
        #pragma unroll
        for (int ct = 0; ct < 4; ++ct) {
            s16x4 b = *(const s16x4*)&Wt[(ct << 4) + (l & 15)][((l >> 4) << 2) + (kc << 4)];
            acc[0][ct] = mfma16(a0, b, acc[0][ct]);
            acc[1][ct] = mfma16(a1, b, acc[1][ct]);
        }
    }
    asm volatile("s_nop 7\n\ts_nop 7");   // MFMA-write -> VALU-read hazard
    #pragma unroll
    for (int rt = 0; rt < 2; ++rt)
    #pragma unroll
    for (int ct = 0; ct < 4; ++ct)
    #pragma unroll
    for (int j = 0; j < 4; ++j) {
        int rloc = w*32 + rt*16 + ((l >> 4) << 2) + j;
        if (STORE_GLOBAL) {
            int rg = rbase + rloc;
            if (rg < n)
                dstg[(size_t)rg * HID + (ct << 4) + (l & 15)] = f2b(acc[rt][ct][j]);
        } else {
            gld[rloc][(ct << 4) + (l & 15)] = f2b(fmaxf(acc[rt][ct][j], 0.f));
        }
    }
}

__global__ __launch_bounds__(256) void node_mlp_mfma(
    const ushort* __restrict__ x16,
    const float* __restrict__ W1, const float* __restrict__ b1,
    const float* __restrict__ W2, const float* __restrict__ b2,
    const float* __restrict__ A12,
    const float* __restrict__ ab,
    ushort* __restrict__ u, ushort* __restrict__ v, int n)
{
    __shared__ ushort Wt[4][64][68];
    __shared__ ushort gld[128][68];
    int tid = threadIdx.x;
    int l = tid & 63, w = tid >> 6;
    int rbase = blockIdx.x * 128;

    const float* Wsrc[4] = { W1, A12, W2, A12 + HID*HID };
    for (int m = 0; m < 4; ++m) {
        const float4* s4 = reinterpret_cast<const float4*>(Wsrc[m]);
        #pragma unroll
        for (int q = 0; q < 4; ++q) {
            float4 t = s4[tid*4 + q];
            int idx = tid*16 + q*4;
            int k = idx >> 6, c = idx & 63;
            Wt[m][c+0][k] = f2b(t.x); Wt[m][c+1][k] = f2b(t.y);
            Wt[m][c+2][k] = f2b(t.z); Wt[m][c+3][k] = f2b(t.w);
        }
    }

    s16x4 afr[2][4];
    #pragma unroll
    for (int rt = 0; rt < 2; ++rt) {
        int r = rbase + w*32 + rt*16 + (l & 15);
        int rc = min(r, n - 1);
        const ushort* xr = x16 + (size_t)rc * HID + ((l >> 4) << 2);
        #pragma unroll
        for (int kc = 0; kc < 4; ++kc)
            afr[rt][kc] = *(const s16x4*)(xr + (kc << 4));
    }
    __syncthreads();

    mfma_stage<true,  false>(afr, Wt[0], b1,      gld, w, l, nullptr, rbase, n);
    mfma_stage<false, true >(afr, Wt[1], ab,      gld, w, l, u,       rbase, n);
    mfma_stage<true,  false>(afr, Wt[2], b2,      gld, w, l, nullptr, rbase, n);
    mfma_stage<false, true >(afr, Wt[3], nullptr, gld, w, l, v,       rbase, n);
}

// ---------------------------------------------------------------------------
// CSR build, radix style: no global atomics, exclusive write segments.
// tmp payload packed to 4B: (row & 255) << 24 | col   (needs n < 2^24)
// ---------------------------------------------------------------------------
__global__ __launch_bounds__(256) void bucket_hist(const int* __restrict__ row,
                                                   int* __restrict__ hist,
                                                   int E, int K, int chunk)
{
    __shared__ int h[KMAX];
    for (int i = threadIdx.x; i < K; i += 256) h[i] = 0;
    __syncthreads();
    int w = blockIdx.x;
    int s = w * chunk, e = min(E, s + chunk);
    for (int i = s + threadIdx.x; i < e; i += 256)
        atomicAdd(&h[row[i] >> BK], 1);
    __syncthreads();
    for (int i = threadIdx.x; i < K; i += 256)
        hist[i * B_WG + w] = h[i];
}

__global__ __launch_bounds__(512) void bucket_base(const int* __restrict__ hist,
                                                   int* __restrict__ bbase,
                                                   int* __restrict__ ptr,
                                                   int K, int E, int n)
{
    __shared__ int lds[512];
    int t = threadIdx.x;
    int total = 0;
    if (t < K) {
        const int* hrow = hist + t * B_WG;
        for (int w = 0; w < B_WG; ++w) total += hrow[w];
    }
    lds[t] = total;
    __syncthreads();
    int val = total;
    for (int off = 1; off < 512; off <<= 1) {
        int tmp = (t >= off) ? lds[t - off] : 0;
        __syncthreads();
        val += tmp;
        lds[t] = val;
        __syncthreads();
    }
    if (t <= K) bbase[t] = val - total;
    if (t == 0) ptr[n] = E;
}

__global__ __launch_bounds__(B_WG) void wg_offsets(const int* __restrict__ hist,
                                                   const int* __restrict__ bbase,
                                                   int* __restrict__ offs)
{
    __shared__ int lds[B_WG];
    int b = blockIdx.x, t = threadIdx.x;
    int v = hist[b * B_WG + t];
    lds[t] = v;
    __syncthreads();
    int val = v;
    for (int off = 1; off < B_WG; off <<= 1) {
        int tmp = (t >= off) ? lds[t - off] : 0;
        __syncthreads();
        val += tmp;
        lds[t] = val;
        __syncthreads();
    }
    offs[b * B_WG + t] = bbase[b] + val - v;
}

__global__ __launch_bounds__(256) void partition_edges(const int* __restrict__ row,
                                                       const int* __restrict__ col,
                                                       const int* __restrict__ offs,
                                                       uint* __restrict__ tmp,
                                                       int E, int K, int chunk)
{
    __shared__ int cur[KMAX];
    int w = blockIdx.x;
    for (int i = threadIdx.x; i < K; i += 256)
        cur[i] = offs[i * B_WG + w];
    __syncthreads();
    int s = w * chunk, e = min(E, s + chunk);
    for (int i = s + threadIdx.x; i < e; i += 256) {
        int r = row[i], c = col[i];
        int pos = atomicAdd(&cur[r >> BK], 1);
        tmp[pos] = ((uint)(r & 255) << 24) | (uint)c;
    }
}

__global__ __launch_bounds__(256) void fine_sort(const uint* __restrict__ tmp,
                                                 const int* __restrict__ bbase,
                                                 int* __restrict__ ptr,
                                                 int* __restrict__ row_sorted,
                                                 int* __restrict__ col_sorted,
                                                 int n)
{
    __shared__ int rcnt[256];
    __shared__ int scan[256];
    __shared__ int cur[256];
    int b = blockIdx.x, t = threadIdx.x;
    int row0 = b << BK;
    rcnt[t] = 0;
    __syncthreads();
    int s = bbase[b], e = bbase[b + 1];
    for (int i = s + t; i < e; i += 256)
        atomicAdd(&rcnt[tmp[i] >> 24], 1);
    __syncthreads();
    int v = rcnt[t];
    scan[t] = v;
    __syncthreads();
    int val = v;
    for (int off = 1; off < 256; off <<= 1) {
        int tm = (t >= off) ? scan[t - off] : 0;
        __syncthreads();
        val += tm;
        scan[t] = val;
        __syncthreads();
    }
    int rstart = s + val - v;
    int r = row0 + t;
    if (r < n) ptr[r] = rstart;
    cur[t] = rstart;
    __syncthreads();
    for (int i = s + t; i < e; i += 256) {
        uint rc = tmp[i];
        int pos = atomicAdd(&cur[rc >> 24], 1);
        row_sorted[pos] = row0 | (int)(rc >> 24);
        col_sorted[pos] = (int)(rc & 0xFFFFFFu);
    }
}

// ---------------------------------------------------------------------------
// Edge mask: 8 lanes per edge, ushort8 (16B) loads, 3-stage reduce
// ---------------------------------------------------------------------------
__global__ __launch_bounds__(256) void edge_mask8(
    const ushort* __restrict__ u, const ushort* __restrict__ v,
    const float* __restrict__ w2, const float* __restrict__ b2p,
    const int* __restrict__ rows, const int* __restrict__ cols,
    float* __restrict__ mask_sorted, int E)
{
    int g = (blockIdx.x * 256 + threadIdx.x) >> 3;
    if (g >= E) return;
    int sub = threadIdx.x & 7;
    int r = rows[g], c = cols[g];
    union { uint4 q; ushort s[8]; } uu, vv;
    uu.q = *reinterpret_cast<const uint4*>(u + (size_t)r * HID + sub * 8);
    vv.q = *reinterpret_cast<const uint4*>(v + (size_t)c * HID + sub * 8);
    float4 wa = *reinterpret_cast<const float4*>(w2 + sub * 8);
    float4 wb = *reinterpret_cast<const float4*>(w2 + sub * 8 + 4);
    float p;
    p =        fmaxf(b2f(uu.s[0]) + b2f(vv.s[0]), 0.f) * wa.x;
    p = fmaf(fmaxf(b2f(uu.s[1]) + b2f(vv.s[1]), 0.f), wa.y, p);
    p = fmaf(fmaxf(b2f(uu.s[2]) + b2f(vv.s[2]), 0.f), wa.z, p);
    p = fmaf(fmaxf(b2f(uu.s[3]) + b2f(vv.s[3]), 0.f), wa.w, p);
    p = fmaf(fmaxf(b2f(uu.s[4]) + b2f(vv.s[4]), 0.f), wb.x, p);
    p = fmaf(fmaxf(b2f(uu.s[5]) + b2f(vv.s[5]), 0.f), wb.y, p);
    p = fmaf(fmaxf(b2f(uu.s[6]) + b2f(vv.s[6]), 0.f), wb.z, p);
    p = fmaf(fmaxf(b2f(uu.s[7]) + b2f(vv.s[7]), 0.f), wb.w, p);
    p += __shfl_xor(p, 1, 64);
    p += __shfl_xor(p, 2, 64);
    p += __shfl_xor(p, 4, 64);
    if (sub == 0) {
        float la = p + b2p[0];
        float s = 1.f / (1.f + __expf(-la));
        mask_sorted[g] = fminf(fmaxf(fmaf(s, 1.5f, -0.45f), 0.f), 1.f);
    }
}

__global__ __launch_bounds__(256) void rowsum_dinv(
    const float* __restrict__ mask_sorted, const int* __restrict__ ptr,
    float* __restrict__ dinv, int n)
{
    int i = blockIdx.x * 256 + threadIdx.x;
    if (i >= n) return;
    int s0 = ptr[i], s1 = ptr[i + 1];
    float s = 1e-6f;
    for (int e = s0; e < s1; ++e) s += mask_sorted[e];
    float d = 1.f / sqrtf(s);
    dinv[i] = fminf(d, 10.f);
}

// ---------------------------------------------------------------------------
// Aggregation: wave-per-node, 2 cols/lane-half, 16-col chunks (zero-padded).
// LAST=false: write res (bf16). LAST=true: fuse out = feat + r1 + r2 + res.
// ---------------------------------------------------------------------------
template<bool LAST>
__global__ __launch_bounds__(256) void agg_csr2(
    const ushort* __restrict__ x16,
    const float* __restrict__ mask_sorted, const float* __restrict__ dinv,
    const int* __restrict__ ptr, const int* __restrict__ col_sorted,
    ushort* __restrict__ x16_out,
    const float* __restrict__ feat, const ushort* __restrict__ r1,
    const ushort* __restrict__ r2, float* __restrict__ out, int n)
{
    int wid = (blockIdx.x * 256 + threadIdx.x) >> 6;
    if (wid >= n) return;
    int lane = threadIdx.x & 63;
    int half = lane >> 5;        // 0: even cols, 1: odd cols
    int d2 = lane & 31;          // dim pair index
    int start = ptr[wid], end = ptr[wid + 1];
    int deg = end - start;
    const ushort* xb = x16 + d2 * 2;   // per-lane base; col offset = c*HID
    float ax = 0.f, ay = 0.f;

    for (int base = 0; base < deg; base += 64) {
        int mcnt = min(64, deg - base);
        int cc = 0; float wv = 0.f;
        if (lane < mcnt) {
            cc = col_sorted[start + base + lane];
            wv = mask_sorted[start + base + lane] * dinv[cc];
        }
        int m16 = (mcnt + 15) & ~15;        // pad; extra lanes carry w=0
        for (int j = 0; j < m16; j += 16) {
            int jj = j + half;
            int   c0 = __shfl(cc, jj,      64);
            int   c1 = __shfl(cc, jj + 2,  64);
            int   c2 = __shfl(cc, jj + 4,  64);
            int   c3 = __shfl(cc, jj + 6,  64);
            int   c4 = __shfl(cc, jj + 8,  64);
            int   c5 = __shfl(cc, jj + 10, 64);
            int   c6 = __shfl(cc, jj + 12, 64);
            int   c7 = __shfl(cc, jj + 14, 64);
            float w0 = __shfl(wv, jj,      64);
            float w1 = __shfl(wv, jj + 2,  64);
            float w2 = __shfl(wv, jj + 4,  64);
            float w3 = __shfl(wv, jj + 6,  64);
            float w4 = __shfl(wv, jj + 8,  64);
            float w5 = __shfl(wv, jj + 10, 64);
            float w6 = __shfl(wv, jj + 12, 64);
            float w7 = __shfl(wv, jj + 14, 64);
            uint p0 = *reinterpret_cast<const uint*>(xb + (size_t)c0 * HID);
            uint p1 = *reinterpret_cast<const uint*>(xb + (size_t)c1 * HID);
            uint p2 = *reinterpret_cast<const uint*>(xb + (size_t)c2 * HID);
            uint p3 = *reinterpret_cast<const uint*>(xb + (size_t)c3 * HID);
            uint p4 = *reinterpret_cast<const uint*>(xb + (size_t)c4 * HID);
            uint p5 = *reinterpret_cast<const uint*>(xb + (size_t)c5 * HID);
            uint p6 = *reinterpret_cast<const uint*>(xb + (size_t)c6 * HID);
            uint p7 = *reinterpret_cast<const uint*>(xb + (size_t)c7 * HID);
            ax = fmaf(w0, b2f((ushort)p0), ax); ay = fmaf(w0, b2f((ushort)(p0 >> 16)), ay);
            ax = fmaf(w1, b2f((ushort)p1), ax); ay = fmaf(w1, b2f((ushort)(p1 >> 16)), ay);
            ax = fmaf(w2, b2f((ushort)p2), ax); ay = fmaf(w2, b2f((ushort)(p2 >> 16)), ay);
            ax = fmaf(w3, b2f((ushort)p3), ax); ay = fmaf(w3, b2f((ushort)(p3 >> 16)), ay);
            ax = fmaf(w4, b2f((ushort)p4), ax); ay = fmaf(w4, b2f((ushort)(p4 >> 16)), ay);
            ax = fmaf(w5, b2f((ushort)p5), ax); ay = fmaf(w5, b2f((ushort)(p5 >> 16)), ay);
            ax = fmaf(w6, b2f((ushort)p6), ax); ay = fmaf(w6, b2f((ushort)(p6 >> 16)), ay);
            ax = fmaf(w7, b2f((ushort)p7), ax); ay = fmaf(w7, b2f((ushort)(p7 >> 16)), ay);
        }
    }
    // combine even/odd halves
    ax += __shfl_xor(ax, 32, 64);
    ay += __shfl_xor(ay, 32, 64);
    if (half == 0) {
        float dv = dinv[wid];
        float rx = ax * dv, ry = ay * dv;
        size_t o2 = (size_t)wid * 32 + d2;
        if (LAST) {
            float2 f = reinterpret_cast<const float2*>(feat)[o2];
            uint a1 = reinterpret_cast<const uint*>(r1)[o2];
            uint a2 = reinterpret_cast<const uint*>(r2)[o2];
            float2 o;
            o.x = f.x + b2f((ushort)a1) + b2f((ushort)a2) + rx;
            o.y = f.y + b2f((ushort)(a1 >> 16)) + b2f((ushort)(a2 >> 16)) + ry;
            reinterpret_cast<float2*>(out)[o2] = o;
        } else {
            uint pk = (uint)f2b(rx) | ((uint)f2b(ry) << 16);
            reinterpret_cast<uint*>(x16_out)[o2] = pk;
        }
    }
}

// ---------------------------------------------------------------------------

extern "C" void kernel_launch(void* const* d_in, const int* in_sizes, int n_in,
                              void* d_out, int out_size, void* d_ws, size_t ws_size,
                              hipStream_t stream)
{
    const float* feat  = (const float*)d_in[0];
    const float* nbW   = (const float*)d_in[1];
    const float* nbb   = (const float*)d_in[2];
    const float* selfW = (const float*)d_in[3];
    const float* selfb = (const float*)d_in[4];
    const float* a1W   = (const float*)d_in[5];
    const float* a1b   = (const float*)d_in[6];
    const float* a2W   = (const float*)d_in[7];
    const float* a2b   = (const float*)d_in[8];
    const int*   row   = (const int*)d_in[9];
    const int*   col   = (const int*)d_in[10];
    float* out = (float*)d_out;

    const int n = in_sizes[0] / HID;
    const int E = in_sizes[9];
    const int L = in_sizes[1] / (HID * HID);
    const size_t NH = (size_t)n * HID;
    const int K = (n + 255) >> BK;
    const int chunk = (E + B_WG - 1) / B_WG;

    char* p = (char*)d_ws;
    ushort* u          = (ushort*)p; p += NH * 2;
    ushort* v          = (ushort*)p; p += NH * 2;
    ushort* xf         = (ushort*)p; p += NH * 2;   // bf16(feat)
    ushort* r1         = (ushort*)p; p += NH * 2;   // res layer 1
    ushort* r2         = (ushort*)p; p += NH * 2;   // res layer 2
    float* dinv        = (float*)p;  p += (size_t)n * 4;
    float* mask_sorted = (float*)p;  p += (size_t)E * 4;
    int*   col_sorted  = (int*)p;    p += (size_t)E * 4;
    int*   row_sorted  = (int*)p;    p += (size_t)E * 4;
    uint*  tmp_rc      = (uint*)p;   p += (size_t)E * 4;
    int*   ptr         = (int*)p;    p += (size_t)(n + 1) * 4;
    int*   hist        = (int*)p;    p += (size_t)KMAX * B_WG * 4;
    int*   offs        = (int*)p;    p += (size_t)KMAX * B_WG * 4;
    int*   bbase       = (int*)p;    p += 1024 * 4;

    const int wBlocks = (int)(((size_t)n * 64 + 255) / 256);
    const int mBlocks = (E + 31) / 32;
    const int nodeBlocks = (n + 127) / 128;

    // ---- CSR build: radix partition, no global atomics ----
    bucket_hist<<<B_WG, 256, 0, stream>>>(row, hist, E, K, chunk);
    bucket_base<<<1, 512, 0, stream>>>(hist, bbase, ptr, K, E, n);
    wg_offsets<<<K, B_WG, 0, stream>>>(hist, bbase, offs);
    partition_edges<<<B_WG, 256, 0, stream>>>(row, col, offs, tmp_rc, E, K, chunk);
    fine_sort<<<K, 256, 0, stream>>>(tmp_rc, bbase, ptr, row_sorted, col_sorted, n);

    // feat -> bf16 (layer-0 x)
    cvt_bf16_kernel<<<(int)((NH / 8 + 255) / 256), 256, 0, stream>>>(feat, xf, (long)(NH / 8));

    ushort* res[2] = { r1, r2 };
    const ushort* x_in = xf;
    for (int l = 0; l < L; ++l) {
        node_mlp_mfma<<<nodeBlocks, 256, 0, stream>>>(
            x_in,
            nbW + (size_t)l * HID * HID,   nbb + (size_t)l * HID,
            selfW + (size_t)l * HID * HID, selfb + (size_t)l * HID,
            a1W + (size_t)l * 2 * HID * HID,
            a1b + (size_t)l * HID,
            u, v, n);

        edge_mask8<<<mBlocks, 256, 0, stream>>>(
            u, v, a2W + (size_t)l * HID, a2b + l,
            row_sorted, col_sorted, mask_sorted, E);

        rowsum_dinv<<<(n + 255) / 256, 256, 0, stream>>>(mask_sorted, ptr, dinv, n);

        if (l == L - 1) {
            agg_csr2<true><<<wBlocks, 256, 0, stream>>>(
                x_in, mask_sorted, dinv, ptr, col_sorted,
                nullptr, feat, r1, r2, out, n);
        } else {
            agg_csr2<false><<<wBlocks, 256, 0, stream>>>(
                x_in, mask_sorted, dinv, ptr, col_sorted,
                res[l], nullptr, nullptr, nullptr, nullptr, n);
            x_in = res[l];
        }
    }
}